// Round 4
// baseline (199.797 us; speedup 1.0000x reference)
//
#include <hip/hip_runtime.h>
#include <math.h>

#define V_NUM 6890
#define NJ 24
#define KTOT 217            // 10 betas + 207 pose_map
#define KP 256              // padded K (multiple of 64)
#define M_DIM (V_NUM * 3)   // 20670
#define MPAD 20736          // 162 * 128
#define VPAD 6912           // 27 * 256

typedef __attribute__((ext_vector_type(8))) short bf16x8;
typedef __attribute__((ext_vector_type(4))) float f32x4;

__constant__ int c_parents[NJ] = {-1,0,0,0,1,2,3,4,5,6,7,8,9,9,9,12,13,14,16,17,18,19,20,21};

__device__ __forceinline__ unsigned short f2bf(float x) {
  union { float f; unsigned int u; } v; v.f = x;
  unsigned int r = v.u + 0x7fffu + ((v.u >> 16) & 1u);
  return (unsigned short)(r >> 16);
}

#define GLOBAL_AS __attribute__((address_space(1)))
#define LDS_AS __attribute__((address_space(3)))
__device__ __forceinline__ void gl_lds16(const void* g, void* l) {
  __builtin_amdgcn_global_load_lds((const GLOBAL_AS unsigned int*)g,
                                   (LDS_AS unsigned int*)l, 16, 0, 0);
}

// ---------------- Kernel A: fold J_regressor into shapedirs/template ----------------
__global__ __launch_bounds__(256) void k_regress(
    const float* __restrict__ JR, const float* __restrict__ SD,
    const float* __restrict__ VT, float* __restrict__ JS, float* __restrict__ Jt) {
  int j = blockIdx.x;
  int tid = threadIdx.x;
  float part[33];
#pragma unroll
  for (int q = 0; q < 33; q++) part[q] = 0.f;
  for (int v = tid; v < V_NUM; v += 256) {
    float jr = JR[j * V_NUM + v];
#pragma unroll
    for (int cc = 0; cc < 3; cc++) {
      part[30 + cc] += jr * VT[v * 3 + cc];
#pragma unroll
      for (int ss = 0; ss < 10; ss++)
        part[cc * 10 + ss] += jr * SD[(v * 3 + cc) * 10 + ss];
    }
  }
  __shared__ float sm[33][4];
  int lane = tid & 63, wid = tid >> 6;
#pragma unroll
  for (int q = 0; q < 33; q++) {
    float x = part[q];
    for (int off = 32; off > 0; off >>= 1) x += __shfl_down(x, off);
    if (lane == 0) sm[q][wid] = x;
  }
  __syncthreads();
  if (tid < 33) {
    float s = sm[tid][0] + sm[tid][1] + sm[tid][2] + sm[tid][3];
    if (tid < 30) JS[j * 30 + tid] = s;
    else Jt[j * 3 + (tid - 30)] = s;
  }
}

// ---------------- Kernel A2: convert A = [shapedirs | posedirs] -> bf16 [MPAD][KP] ----------------
__global__ __launch_bounds__(256) void k_convA(
    const float* __restrict__ SD, const float* __restrict__ PD,
    unsigned short* __restrict__ Abf) {
  int m = blockIdx.x;
  int k = threadIdx.x;
  float v = 0.f;
  if (m < M_DIM && k < KTOT)
    v = (k < 10) ? SD[(size_t)m * 10 + k] : PD[(size_t)m * 207 + (k - 10)];
  Abf[(size_t)m * KP + k] = f2bf(v);
}

// ---------------- Kernel A3: convert W -> bf16 fragment-ready [VPAD][32] ----------------
__global__ __launch_bounds__(256) void k_convW(
    const float* __restrict__ W, unsigned short* __restrict__ Wbf) {
  int idx = blockIdx.x * 256 + threadIdx.x;   // over VPAD*32
  if (idx >= VPAD * 32) return;
  int v = idx >> 5, k = idx & 31;
  Wbf[idx] = (v < V_NUM && k < NJ) ? f2bf(W[(size_t)v * NJ + k]) : (unsigned short)0;
}

// ---------------- Kernel B: per-batch rodrigues + joints + kinematic chain ----------------
// Writes: Kcb [B][KP] bf16, GrelP [B][16][40] bf16 (GrelT: row c=p*4+q, col j; zero-pad),
//         outG [B][24][16], outJtr [B][24][3]
__global__ __launch_bounds__(64) void k_batch(
    const float* __restrict__ pose, const float* __restrict__ betas,
    const float* __restrict__ trans, const float* __restrict__ JS,
    const float* __restrict__ Jt, unsigned short* __restrict__ Kcb,
    unsigned short* __restrict__ GrelP, float* __restrict__ outG,
    float* __restrict__ outJtr, int B) {
  int b = blockIdx.x;
  int lane = threadIdx.x;
  __shared__ float rotS[NJ][9];
  __shared__ float jS[NJ * 3];
  __shared__ float Gs[NJ][12];
  __shared__ float GrS[NJ][12];

  if (lane < NJ) {
    float rx = pose[b * 72 + lane * 3 + 0];
    float ry = pose[b * 72 + lane * 3 + 1];
    float rz = pose[b * 72 + lane * 3 + 2];
    float a2 = rx * rx + ry * ry + rz * rz + 1e-16f;
    float ang = sqrtf(a2);
    float inv = 1.f / ang;
    float ux = rx * inv, uy = ry * inv, uz = rz * inv;
    float c = cosf(ang), s = sinf(ang), ic = 1.f - c;
    float R[9];
    R[0] = c + ic * ux * ux;      R[1] = ic * ux * uy - s * uz; R[2] = ic * ux * uz + s * uy;
    R[3] = ic * uy * ux + s * uz; R[4] = c + ic * uy * uy;      R[5] = ic * uy * uz - s * ux;
    R[6] = ic * uz * ux - s * uy; R[7] = ic * uz * uy + s * ux; R[8] = c + ic * uz * uz;
#pragma unroll
    for (int k = 0; k < 9; k++) rotS[lane][k] = R[k];
    if (lane > 0) {
#pragma unroll
      for (int k = 0; k < 9; k++) {
        float iden = (k == 0 || k == 4 || k == 8) ? 1.f : 0.f;
        Kcb[(size_t)b * KP + 10 + (lane - 1) * 9 + k] = f2bf(R[k] - iden);
      }
    }
  }
  if (lane < 10) Kcb[(size_t)b * KP + lane] = f2bf(betas[b * 10 + lane]);
  if (lane < KP - KTOT) Kcb[(size_t)b * KP + KTOT + lane] = 0;

  __syncthreads();
  for (int idx = lane; idx < 72; idx += 64) {
    float s = Jt[idx];
#pragma unroll
    for (int ss = 0; ss < 10; ss++) s += JS[idx * 10 + ss] * betas[b * 10 + ss];
    jS[idx] = s;
  }
  __syncthreads();

  if (lane == 0) {
#pragma unroll
    for (int p = 0; p < 3; p++) {
      Gs[0][p * 4 + 0] = rotS[0][p * 3 + 0];
      Gs[0][p * 4 + 1] = rotS[0][p * 3 + 1];
      Gs[0][p * 4 + 2] = rotS[0][p * 3 + 2];
      Gs[0][p * 4 + 3] = jS[p];
    }
    for (int i = 1; i < NJ; i++) {
      int par = c_parents[i];
      float t0 = jS[i * 3 + 0] - jS[par * 3 + 0];
      float t1 = jS[i * 3 + 1] - jS[par * 3 + 1];
      float t2 = jS[i * 3 + 2] - jS[par * 3 + 2];
#pragma unroll
      for (int p = 0; p < 3; p++) {
        float rp0 = Gs[par][p * 4 + 0], rp1 = Gs[par][p * 4 + 1], rp2 = Gs[par][p * 4 + 2];
#pragma unroll
        for (int q = 0; q < 3; q++) {
          Gs[i][p * 4 + q] = rp0 * rotS[i][0 * 3 + q] + rp1 * rotS[i][1 * 3 + q] + rp2 * rotS[i][2 * 3 + q];
        }
        Gs[i][p * 4 + 3] = rp0 * t0 + rp1 * t1 + rp2 * t2 + Gs[par][p * 4 + 3];
      }
    }
    for (int i = 0; i < NJ; i++) {
      float jx = jS[i * 3 + 0], jy = jS[i * 3 + 1], jz = jS[i * 3 + 2];
#pragma unroll
      for (int p = 0; p < 3; p++) {
        float g0 = Gs[i][p * 4 + 0], g1 = Gs[i][p * 4 + 1], g2 = Gs[i][p * 4 + 2];
        GrS[i][p * 4 + 0] = g0;
        GrS[i][p * 4 + 1] = g1;
        GrS[i][p * 4 + 2] = g2;
        GrS[i][p * 4 + 3] = Gs[i][p * 4 + 3] - (g0 * jx + g1 * jy + g2 * jz);
      }
    }
  }
  __syncthreads();

  for (int idx = lane; idx < NJ * 16; idx += 64) {
    int jj = idx >> 4, rc = idx & 15, p = rc >> 2, q = rc & 3;
    float val = (p < 3) ? Gs[jj][p * 4 + q] : ((q == 3) ? 1.f : 0.f);
    outG[(size_t)b * NJ * 16 + idx] = val;
  }
  for (int idx = lane; idx < NJ * 3; idx += 64) {
    int jj = idx / 3, p = idx % 3;
    outJtr[(size_t)b * NJ * 3 + idx] = Gs[jj][p * 4 + 3] + trans[b * 3 + p];
  }
  // GrelT bf16 panel: [c=0..15][j=0..39], zeros outside c<12, j<24
  for (int idx = lane; idx < 16 * 40; idx += 64) {
    int c = idx / 40, j = idx % 40;
    GrelP[(size_t)b * 640 + idx] = (c < 12 && j < NJ) ? f2bf(GrS[j][c]) : (unsigned short)0;
  }
}

// ---------------- Kernel C: MFMA GEMM  D[b][m] = sum_k Kcb[b][k] * Abf[m][k] + VT[m] ----------------
__global__ __launch_bounds__(256) void k_pose_mfma(
    const unsigned short* __restrict__ Kcb, const unsigned short* __restrict__ Abf,
    const float* __restrict__ VT,
    float* __restrict__ outVP, float* __restrict__ outNK, int B) {
  __shared__ unsigned short At[128 * 64];
  __shared__ unsigned short Bt[128 * 64];
  const int tid = threadIdx.x;
  const int lane = tid & 63;
  const int w = tid >> 6;
  const int wr = w >> 1, wc = w & 1;
  const int b0 = blockIdx.y * 128;
  const int m0 = blockIdx.x * 128;

  f32x4 acc[4][4];
#pragma unroll
  for (int i = 0; i < 4; i++)
#pragma unroll
    for (int j = 0; j < 4; j++) acc[i][j] = (f32x4){0.f, 0.f, 0.f, 0.f};

  int Lrow[4], Lkb[4];
#pragma unroll
  for (int i = 0; i < 4; i++) {
    int L = w * 4096 + i * 1024 + lane * 16;
    int row = L >> 7;
    int kb = (L & 127) ^ ((row & 7) << 4);
    Lrow[i] = row;
    Lkb[i] = kb >> 1;
  }

  for (int kt = 0; kt < KP / 64; ++kt) {
#pragma unroll
    for (int i = 0; i < 4; i++) {
      const unsigned short* gA = Kcb + (size_t)(b0 + Lrow[i]) * KP + kt * 64 + Lkb[i];
      gl_lds16(gA, (char*)At + w * 4096 + i * 1024);
    }
#pragma unroll
    for (int i = 0; i < 4; i++) {
      const unsigned short* gB = Abf + (size_t)(m0 + Lrow[i]) * KP + kt * 64 + Lkb[i];
      gl_lds16(gB, (char*)Bt + w * 4096 + i * 1024);
    }
    __syncthreads();

#pragma unroll
    for (int h = 0; h < 2; ++h) {
      bf16x8 af[4], bfr[4];
#pragma unroll
      for (int fi = 0; fi < 4; fi++) {
        int row = wr * 64 + fi * 16 + (lane & 15);
        int byte = (row << 7) + ((h * 64 + ((lane >> 4) << 4)) ^ ((row & 7) << 4));
        af[fi] = *(const bf16x8*)((const char*)At + byte);
      }
#pragma unroll
      for (int fj = 0; fj < 4; fj++) {
        int row = wc * 64 + fj * 16 + (lane & 15);
        int byte = (row << 7) + ((h * 64 + ((lane >> 4) << 4)) ^ ((row & 7) << 4));
        bfr[fj] = *(const bf16x8*)((const char*)Bt + byte);
      }
#pragma unroll
      for (int fi = 0; fi < 4; fi++)
#pragma unroll
        for (int fj = 0; fj < 4; fj++)
          acc[fi][fj] = __builtin_amdgcn_mfma_f32_16x16x32_bf16(af[fi], bfr[fj], acc[fi][fj], 0, 0, 0);
    }
    __syncthreads();
  }

#pragma unroll
  for (int fj = 0; fj < 4; fj++) {
    int cm = m0 + wc * 64 + fj * 16 + (lane & 15);
    if (cm >= M_DIM) continue;
    float vt = VT[cm];
#pragma unroll
    for (int fi = 0; fi < 4; fi++) {
      int rb = b0 + wr * 64 + fi * 16 + ((lane >> 4) << 2);
#pragma unroll
      for (int r = 0; r < 4; r++) {
        float val = acc[fi][fj][r] + vt;
        size_t o = (size_t)(rb + r) * M_DIM + cm;
        outVP[o] = val;
        outNK[o] = val;
      }
    }
  }
}

// ---------------- Kernel D: MFMA skinning, one batch per block, no LDS, no barriers ----------------
// Block (vt, b): 256 verts of batch b. T[c][v] = sum_j GrelT[c][j]*W[v][j] via
// mfma_f32_16x16x32_bf16; lane p=lane>>4 holds T rows 4p..4p+3 of vert (lane&15)+16*sub.
__global__ __launch_bounds__(256) void k_skin2(
    const float* __restrict__ NK, const unsigned short* __restrict__ Wbf,
    const unsigned short* __restrict__ GrelP, const float* __restrict__ trans,
    float* __restrict__ outVerts, int B) {
  const int tid = threadIdx.x;
  const int lane = tid & 63;
  const int w = tid >> 6;
  const int v0 = blockIdx.x * 256;
  const int b = blockIdx.y;
  const int p = lane >> 4;         // output coord row (3 = idle)
  const int kb = p * 8;            // k-base of this lane's fragment
  const int vl16 = lane & 15;

  // A-fragment: GrelT[c=vl16][kb..kb+7] direct from global (L2-resident, 16B aligned)
  bf16x8 af = *(const bf16x8*)(GrelP + (size_t)b * 640 + vl16 * 40 + kb);
  float tp = (p < 3) ? trans[b * 3 + p] : 0.f;
  const float* nkb = NK + (size_t)b * M_DIM;

#pragma unroll
  for (int sub = 0; sub < 4; sub++) {
    int vloc = w * 64 + sub * 16 + vl16;
    int vg = v0 + vloc;
    // B-fragment: Wbf[vg][kb..kb+7] (padded buffer, always in-bounds)
    bf16x8 wf = *(const bf16x8*)(Wbf + (size_t)vg * 32 + kb);
    f32x4 acc = (f32x4){0.f, 0.f, 0.f, 0.f};
    acc = __builtin_amdgcn_mfma_f32_16x16x32_bf16(af, wf, acc, 0, 0, 0);
    if (p < 3 && vg < V_NUM) {
      const float* xp = nkb + (size_t)vg * 3;
      float outv = acc[0] * xp[0] + acc[1] * xp[1] + acc[2] * xp[2] + acc[3] + tp;
      outVerts[(size_t)b * M_DIM + (size_t)vg * 3 + p] = outv;
    }
  }
}

extern "C" void kernel_launch(void* const* d_in, const int* in_sizes, int n_in,
                              void* d_out, int out_size, void* d_ws, size_t ws_size,
                              hipStream_t stream) {
  const float* pose  = (const float*)d_in[0];
  const float* betas = (const float*)d_in[1];
  const float* trans = (const float*)d_in[2];
  const float* vt    = (const float*)d_in[3];
  const float* sd    = (const float*)d_in[4];
  const float* pd    = (const float*)d_in[5];
  const float* jreg  = (const float*)d_in[6];
  const float* wgt   = (const float*)d_in[7];
  int B = in_sizes[0] / 72;

  float* out = (float*)d_out;
  size_t nvb = (size_t)B * M_DIM;
  float* o_verts = out;
  float* o_jtr   = o_verts + nvb;
  float* o_vp    = o_jtr + (size_t)B * NJ * 3;
  float* o_nk    = o_vp + nvb;
  float* o_G     = o_nk + nvb;

  char* wsb = (char*)d_ws;
  float* JS = (float*)wsb;                          // 720 f32
  float* Jt = JS + 720;                             // 72 f32
  size_t off = (720 + 72) * 4;                      // 3168 B (16-aligned)
  unsigned short* Kcb   = (unsigned short*)(wsb + off);                       // B*KP
  unsigned short* Abf   = (unsigned short*)(wsb + off + (size_t)B * KP * 2);  // MPAD*KP
  unsigned short* GrelP = Abf + (size_t)MPAD * KP;                            // B*640
  unsigned short* Wbf   = GrelP + (size_t)B * 640;                            // VPAD*32

  k_regress<<<24, 256, 0, stream>>>(jreg, sd, vt, JS, Jt);
  k_convA<<<MPAD, 256, 0, stream>>>(sd, pd, Abf);
  k_convW<<<(VPAD * 32 + 255) / 256, 256, 0, stream>>>(wgt, Wbf);
  k_batch<<<B, 64, 0, stream>>>(pose, betas, trans, JS, Jt, Kcb, GrelP, o_G, o_jtr, B);
  dim3 gC(MPAD / 128, B / 128);
  k_pose_mfma<<<gC, 256, 0, stream>>>(Kcb, Abf, vt, o_vp, o_nk, B);
  dim3 gD(VPAD / 256, B);
  k_skin2<<<gD, 256, 0, stream>>>(o_nk, Wbf, GrelP, trans, o_verts, B);
}

// Round 5
// 168.054 us; speedup vs baseline: 1.1889x; 1.1889x over previous
//
#include <hip/hip_runtime.h>
#include <math.h>

#define V_NUM 6890
#define NJ 24
#define KTOT 217            // 10 betas + 207 pose_map
#define KP 256              // padded K (multiple of 64)
#define M_DIM (V_NUM * 3)   // 20670
#define MPAD 20736          // 162 * 128
#define VPAD 6912           // 27 * 256

typedef __attribute__((ext_vector_type(8))) short bf16x8;
typedef __attribute__((ext_vector_type(4))) float f32x4;

__constant__ int c_parents[NJ] = {-1,0,0,0,1,2,3,4,5,6,7,8,9,9,9,12,13,14,16,17,18,19,20,21};

__device__ __forceinline__ unsigned short f2bf(float x) {
  union { float f; unsigned int u; } v; v.f = x;
  unsigned int r = v.u + 0x7fffu + ((v.u >> 16) & 1u);
  return (unsigned short)(r >> 16);
}

#define GLOBAL_AS __attribute__((address_space(1)))
#define LDS_AS __attribute__((address_space(3)))
__device__ __forceinline__ void gl_lds16(const void* g, void* l) {
  __builtin_amdgcn_global_load_lds((const GLOBAL_AS unsigned int*)g,
                                   (LDS_AS unsigned int*)l, 16, 0, 0);
}

// ---------------- Kernel A: fold J_regressor into shapedirs/template ----------------
__global__ __launch_bounds__(256) void k_regress(
    const float* __restrict__ JR, const float* __restrict__ SD,
    const float* __restrict__ VT, float* __restrict__ JS, float* __restrict__ Jt) {
  int j = blockIdx.x;
  int tid = threadIdx.x;
  float part[33];
#pragma unroll
  for (int q = 0; q < 33; q++) part[q] = 0.f;
  for (int v = tid; v < V_NUM; v += 256) {
    float jr = JR[j * V_NUM + v];
#pragma unroll
    for (int cc = 0; cc < 3; cc++) {
      part[30 + cc] += jr * VT[v * 3 + cc];
#pragma unroll
      for (int ss = 0; ss < 10; ss++)
        part[cc * 10 + ss] += jr * SD[(v * 3 + cc) * 10 + ss];
    }
  }
  __shared__ float sm[33][4];
  int lane = tid & 63, wid = tid >> 6;
#pragma unroll
  for (int q = 0; q < 33; q++) {
    float x = part[q];
    for (int off = 32; off > 0; off >>= 1) x += __shfl_down(x, off);
    if (lane == 0) sm[q][wid] = x;
  }
  __syncthreads();
  if (tid < 33) {
    float s = sm[tid][0] + sm[tid][1] + sm[tid][2] + sm[tid][3];
    if (tid < 30) JS[j * 30 + tid] = s;
    else Jt[j * 3 + (tid - 30)] = s;
  }
}

// ---------------- Kernel A2: convert A = [shapedirs | posedirs] -> bf16 [MPAD][KP] ----------------
__global__ __launch_bounds__(256) void k_convA(
    const float* __restrict__ SD, const float* __restrict__ PD,
    unsigned short* __restrict__ Abf) {
  int m = blockIdx.x;
  int k = threadIdx.x;
  float v = 0.f;
  if (m < M_DIM && k < KTOT)
    v = (k < 10) ? SD[(size_t)m * 10 + k] : PD[(size_t)m * 207 + (k - 10)];
  Abf[(size_t)m * KP + k] = f2bf(v);
}

// ---------------- Kernel A3: convert W -> bf16 fragment-ready [VPAD][32] ----------------
__global__ __launch_bounds__(256) void k_convW(
    const float* __restrict__ W, unsigned short* __restrict__ Wbf) {
  int idx = blockIdx.x * 256 + threadIdx.x;
  if (idx >= VPAD * 32) return;
  int v = idx >> 5, k = idx & 31;
  Wbf[idx] = (v < V_NUM && k < NJ) ? f2bf(W[(size_t)v * NJ + k]) : (unsigned short)0;
}

// ---------------- Kernel B: per-batch rodrigues + joints + kinematic chain ----------------
__global__ __launch_bounds__(64) void k_batch(
    const float* __restrict__ pose, const float* __restrict__ betas,
    const float* __restrict__ trans, const float* __restrict__ JS,
    const float* __restrict__ Jt, unsigned short* __restrict__ Kcb,
    unsigned short* __restrict__ GrelP, float* __restrict__ outG,
    float* __restrict__ outJtr, int B) {
  int b = blockIdx.x;
  int lane = threadIdx.x;
  __shared__ float rotS[NJ][9];
  __shared__ float jS[NJ * 3];
  __shared__ float Gs[NJ][12];
  __shared__ float GrS[NJ][12];

  if (lane < NJ) {
    float rx = pose[b * 72 + lane * 3 + 0];
    float ry = pose[b * 72 + lane * 3 + 1];
    float rz = pose[b * 72 + lane * 3 + 2];
    float a2 = rx * rx + ry * ry + rz * rz + 1e-16f;
    float ang = sqrtf(a2);
    float inv = 1.f / ang;
    float ux = rx * inv, uy = ry * inv, uz = rz * inv;
    float c = cosf(ang), s = sinf(ang), ic = 1.f - c;
    float R[9];
    R[0] = c + ic * ux * ux;      R[1] = ic * ux * uy - s * uz; R[2] = ic * ux * uz + s * uy;
    R[3] = ic * uy * ux + s * uz; R[4] = c + ic * uy * uy;      R[5] = ic * uy * uz - s * ux;
    R[6] = ic * uz * ux - s * uy; R[7] = ic * uz * uy + s * ux; R[8] = c + ic * uz * uz;
#pragma unroll
    for (int k = 0; k < 9; k++) rotS[lane][k] = R[k];
    if (lane > 0) {
#pragma unroll
      for (int k = 0; k < 9; k++) {
        float iden = (k == 0 || k == 4 || k == 8) ? 1.f : 0.f;
        Kcb[(size_t)b * KP + 10 + (lane - 1) * 9 + k] = f2bf(R[k] - iden);
      }
    }
  }
  if (lane < 10) Kcb[(size_t)b * KP + lane] = f2bf(betas[b * 10 + lane]);
  if (lane < KP - KTOT) Kcb[(size_t)b * KP + KTOT + lane] = 0;

  __syncthreads();
  for (int idx = lane; idx < 72; idx += 64) {
    float s = Jt[idx];
#pragma unroll
    for (int ss = 0; ss < 10; ss++) s += JS[idx * 10 + ss] * betas[b * 10 + ss];
    jS[idx] = s;
  }
  __syncthreads();

  if (lane == 0) {
#pragma unroll
    for (int p = 0; p < 3; p++) {
      Gs[0][p * 4 + 0] = rotS[0][p * 3 + 0];
      Gs[0][p * 4 + 1] = rotS[0][p * 3 + 1];
      Gs[0][p * 4 + 2] = rotS[0][p * 3 + 2];
      Gs[0][p * 4 + 3] = jS[p];
    }
    for (int i = 1; i < NJ; i++) {
      int par = c_parents[i];
      float t0 = jS[i * 3 + 0] - jS[par * 3 + 0];
      float t1 = jS[i * 3 + 1] - jS[par * 3 + 1];
      float t2 = jS[i * 3 + 2] - jS[par * 3 + 2];
#pragma unroll
      for (int p = 0; p < 3; p++) {
        float rp0 = Gs[par][p * 4 + 0], rp1 = Gs[par][p * 4 + 1], rp2 = Gs[par][p * 4 + 2];
#pragma unroll
        for (int q = 0; q < 3; q++) {
          Gs[i][p * 4 + q] = rp0 * rotS[i][0 * 3 + q] + rp1 * rotS[i][1 * 3 + q] + rp2 * rotS[i][2 * 3 + q];
        }
        Gs[i][p * 4 + 3] = rp0 * t0 + rp1 * t1 + rp2 * t2 + Gs[par][p * 4 + 3];
      }
    }
    for (int i = 0; i < NJ; i++) {
      float jx = jS[i * 3 + 0], jy = jS[i * 3 + 1], jz = jS[i * 3 + 2];
#pragma unroll
      for (int p = 0; p < 3; p++) {
        float g0 = Gs[i][p * 4 + 0], g1 = Gs[i][p * 4 + 1], g2 = Gs[i][p * 4 + 2];
        GrS[i][p * 4 + 0] = g0;
        GrS[i][p * 4 + 1] = g1;
        GrS[i][p * 4 + 2] = g2;
        GrS[i][p * 4 + 3] = Gs[i][p * 4 + 3] - (g0 * jx + g1 * jy + g2 * jz);
      }
    }
  }
  __syncthreads();

  for (int idx = lane; idx < NJ * 16; idx += 64) {
    int jj = idx >> 4, rc = idx & 15, p = rc >> 2, q = rc & 3;
    float val = (p < 3) ? Gs[jj][p * 4 + q] : ((q == 3) ? 1.f : 0.f);
    outG[(size_t)b * NJ * 16 + idx] = val;
  }
  for (int idx = lane; idx < NJ * 3; idx += 64) {
    int jj = idx / 3, p = idx % 3;
    outJtr[(size_t)b * NJ * 3 + idx] = Gs[jj][p * 4 + 3] + trans[b * 3 + p];
  }
  // GrelT bf16 panel: [c=0..15][j=0..39], zeros outside c<12, j<24
  for (int idx = lane; idx < 16 * 40; idx += 64) {
    int c = idx / 40, j = idx % 40;
    GrelP[(size_t)b * 640 + idx] = (c < 12 && j < NJ) ? f2bf(GrS[j][c]) : (unsigned short)0;
  }
}

// ---------------- Kernel C: MFMA GEMM  D[m][b] tiles; rows = m (4 consecutive per lane) ----------------
// acc[i][j] = mfma(fm[i] (Abf rows=m), fb[j] (Kcb rows=b)) -> D row=m, col=b.
// Lane holds 4 consecutive m for one b -> vectorized stores.
__global__ __launch_bounds__(256) void k_pose_mfma(
    const unsigned short* __restrict__ Kcb, const unsigned short* __restrict__ Abf,
    const float* __restrict__ VT,
    float* __restrict__ outVP, float* __restrict__ outNK, int B) {
  __shared__ unsigned short At[128 * 64];  // Kcb rows (b-local)
  __shared__ unsigned short Bt[128 * 64];  // Abf rows (m-local)
  const int tid = threadIdx.x;
  const int lane = tid & 63;
  const int w = tid >> 6;
  const int wr = w >> 1, wc = w & 1;       // wr -> m half, wc -> b half
  const int b0 = blockIdx.y * 128;
  const int m0 = blockIdx.x * 128;

  f32x4 acc[4][4];
#pragma unroll
  for (int i = 0; i < 4; i++)
#pragma unroll
    for (int j = 0; j < 4; j++) acc[i][j] = (f32x4){0.f, 0.f, 0.f, 0.f};

  int Lrow[4], Lkb[4];
#pragma unroll
  for (int i = 0; i < 4; i++) {
    int L = w * 4096 + i * 1024 + lane * 16;
    int row = L >> 7;
    int kb = (L & 127) ^ ((row & 7) << 4);
    Lrow[i] = row;
    Lkb[i] = kb >> 1;
  }

  for (int kt = 0; kt < KP / 64; ++kt) {
#pragma unroll
    for (int i = 0; i < 4; i++) {
      const unsigned short* gA = Kcb + (size_t)(b0 + Lrow[i]) * KP + kt * 64 + Lkb[i];
      gl_lds16(gA, (char*)At + w * 4096 + i * 1024);
    }
#pragma unroll
    for (int i = 0; i < 4; i++) {
      const unsigned short* gB = Abf + (size_t)(m0 + Lrow[i]) * KP + kt * 64 + Lkb[i];
      gl_lds16(gB, (char*)Bt + w * 4096 + i * 1024);
    }
    __syncthreads();

#pragma unroll
    for (int h = 0; h < 2; ++h) {
      bf16x8 fm[4], fb[4];
#pragma unroll
      for (int fi = 0; fi < 4; fi++) {
        int row = wr * 64 + fi * 16 + (lane & 15);
        int byte = (row << 7) + ((h * 64 + ((lane >> 4) << 4)) ^ ((row & 7) << 4));
        fm[fi] = *(const bf16x8*)((const char*)Bt + byte);
      }
#pragma unroll
      for (int fj = 0; fj < 4; fj++) {
        int row = wc * 64 + fj * 16 + (lane & 15);
        int byte = (row << 7) + ((h * 64 + ((lane >> 4) << 4)) ^ ((row & 7) << 4));
        fb[fj] = *(const bf16x8*)((const char*)At + byte);
      }
#pragma unroll
      for (int fi = 0; fi < 4; fi++)
#pragma unroll
        for (int fj = 0; fj < 4; fj++)
          acc[fi][fj] = __builtin_amdgcn_mfma_f32_16x16x32_bf16(fm[fi], fb[fj], acc[fi][fj], 0, 0, 0);
    }
    __syncthreads();
  }

  // epilogue: D row = m (4 consecutive per lane), col = b
#pragma unroll
  for (int fj = 0; fj < 4; fj++) {
    int cb = b0 + wc * 64 + fj * 16 + (lane & 15);
    size_t rowbase = (size_t)cb * M_DIM;
#pragma unroll
    for (int fi = 0; fi < 4; fi++) {
      int m = m0 + wr * 64 + fi * 16 + ((lane >> 4) << 2);
      f32x4 v = acc[fi][fj];
      if (m + 3 < M_DIM) {
        const float4 vt4 = *(const float4*)(VT + m);
        float2 lo = {v[0] + vt4.x, v[1] + vt4.y};
        float2 hi = {v[2] + vt4.z, v[3] + vt4.w};
        size_t o = rowbase + m;
        *(float2*)(outVP + o) = lo;
        *(float2*)(outVP + o + 2) = hi;
        *(float2*)(outNK + o) = lo;
        *(float2*)(outNK + o + 2) = hi;
      } else {
#pragma unroll
        for (int r = 0; r < 4; r++) {
          if (m + r < M_DIM) {
            float val = v[r] + VT[m + r];
            outVP[rowbase + m + r] = val;
            outNK[rowbase + m + r] = val;
          }
        }
      }
    }
  }
}

// ---------------- Kernel D: MFMA skinning with per-lane vert ownership ----------------
// Wave owns 64 verts; loops 8 batches. T built by 4 MFMAs (col=vert16, rows=c),
// round-tripped through wave-private LDS [64 verts][13 f32] so each LANE owns one
// vert for the coalesced NK load / apply / store (768B-contiguous per wave).
__global__ __launch_bounds__(256) void k_skin3(
    const float* __restrict__ NK, const unsigned short* __restrict__ Wbf,
    const unsigned short* __restrict__ GrelP, const float* __restrict__ trans,
    float* __restrict__ outVerts, int B) {
  __shared__ float Tl[4][64 * 13];
  const int tid = threadIdx.x;
  const int lane = tid & 63;
  const int w = tid >> 6;
  const int vl16 = lane & 15;
  const int p = lane >> 4;        // c-row group (3 = zero rows)
  const int kb = p * 8;           // k-base of this lane's fragment
  const int vbase = blockIdx.x * 256 + w * 64;
  const int b0 = blockIdx.y * 8;
  const int vg = vbase + lane;    // this lane's owned vert

  // W B-fragments, reused across 8 batches (rows = verts)
  bf16x8 wf[4];
#pragma unroll
  for (int sub = 0; sub < 4; sub++)
    wf[sub] = *(const bf16x8*)(Wbf + (size_t)(vbase + sub * 16 + vl16) * 32 + kb);

  float* myT = Tl[w];

  for (int bi = 0; bi < 8; bi++) {
    int b = b0 + bi;
    // A-fragment: GrelT[c=vl16][kb..kb+7]
    bf16x8 af = *(const bf16x8*)(GrelP + (size_t)b * 640 + vl16 * 40 + kb);
    f32x4 acc[4];
#pragma unroll
    for (int sub = 0; sub < 4; sub++) {
      f32x4 z = (f32x4){0.f, 0.f, 0.f, 0.f};
      acc[sub] = __builtin_amdgcn_mfma_f32_16x16x32_bf16(af, wf[sub], z, 0, 0, 0);
    }
    // scatter T to LDS: T[vert][c], c = p*4 + r
    if (p < 3) {
#pragma unroll
      for (int sub = 0; sub < 4; sub++) {
        int vi = sub * 16 + vl16;
#pragma unroll
        for (int r = 0; r < 4; r++)
          myT[vi * 13 + p * 4 + r] = acc[sub][r];
      }
    }
    asm volatile("s_waitcnt lgkmcnt(0)" ::: "memory");
    __builtin_amdgcn_sched_barrier(0);
    // per-lane vert apply (coalesced)
    if (vg < V_NUM) {
      float t[12];
#pragma unroll
      for (int c = 0; c < 12; c++) t[c] = myT[lane * 13 + c];
      const float* xp = NK + (size_t)b * M_DIM + (size_t)vg * 3;
      float x0 = xp[0], x1 = xp[1], x2 = xp[2];
      float* op = outVerts + (size_t)b * M_DIM + (size_t)vg * 3;
      op[0] = t[0] * x0 + t[1] * x1 + t[2] * x2 + t[3] + trans[b * 3 + 0];
      op[1] = t[4] * x0 + t[5] * x1 + t[6] * x2 + t[7] + trans[b * 3 + 1];
      op[2] = t[8] * x0 + t[9] * x1 + t[10] * x2 + t[11] + trans[b * 3 + 2];
    }
    asm volatile("s_waitcnt lgkmcnt(0)" ::: "memory");
    __builtin_amdgcn_sched_barrier(0);
  }
}

extern "C" void kernel_launch(void* const* d_in, const int* in_sizes, int n_in,
                              void* d_out, int out_size, void* d_ws, size_t ws_size,
                              hipStream_t stream) {
  const float* pose  = (const float*)d_in[0];
  const float* betas = (const float*)d_in[1];
  const float* trans = (const float*)d_in[2];
  const float* vt    = (const float*)d_in[3];
  const float* sd    = (const float*)d_in[4];
  const float* pd    = (const float*)d_in[5];
  const float* jreg  = (const float*)d_in[6];
  const float* wgt   = (const float*)d_in[7];
  int B = in_sizes[0] / 72;

  float* out = (float*)d_out;
  size_t nvb = (size_t)B * M_DIM;
  float* o_verts = out;
  float* o_jtr   = o_verts + nvb;
  float* o_vp    = o_jtr + (size_t)B * NJ * 3;
  float* o_nk    = o_vp + nvb;
  float* o_G     = o_nk + nvb;

  char* wsb = (char*)d_ws;
  float* JS = (float*)wsb;                          // 720 f32
  float* Jt = JS + 720;                             // 72 f32
  size_t off = (720 + 72) * 4;                      // 3168 B (16-aligned)
  unsigned short* Kcb   = (unsigned short*)(wsb + off);                       // B*KP
  unsigned short* Abf   = (unsigned short*)(wsb + off + (size_t)B * KP * 2);  // MPAD*KP
  unsigned short* GrelP = Abf + (size_t)MPAD * KP;                            // B*640
  unsigned short* Wbf   = GrelP + (size_t)B * 640;                            // VPAD*32

  k_regress<<<24, 256, 0, stream>>>(jreg, sd, vt, JS, Jt);
  k_convA<<<MPAD, 256, 0, stream>>>(sd, pd, Abf);
  k_convW<<<(VPAD * 32 + 255) / 256, 256, 0, stream>>>(wgt, Wbf);
  k_batch<<<B, 64, 0, stream>>>(pose, betas, trans, JS, Jt, Kcb, GrelP, o_G, o_jtr, B);
  dim3 gC(MPAD / 128, B / 128);
  k_pose_mfma<<<gC, 256, 0, stream>>>(Kcb, Abf, vt, o_vp, o_nk, B);
  dim3 gD(VPAD / 256, B / 8);
  k_skin3<<<gD, 256, 0, stream>>>(o_nk, Wbf, GrelP, trans, o_verts, B);
}

// Round 6
// 153.338 us; speedup vs baseline: 1.3030x; 1.0960x over previous
//
#include <hip/hip_runtime.h>
#include <math.h>

#define V_NUM 6890
#define NJ 24
#define KTOT 217            // 10 betas + 207 pose_map
#define KP 256              // padded K (multiple of 64)
#define M_DIM (V_NUM * 3)   // 20670
#define MPAD 20736          // 162 * 128
#define VPAD 6912           // 27 * 256

typedef __attribute__((ext_vector_type(8))) short bf16x8;
typedef __attribute__((ext_vector_type(4))) float f32x4;

__constant__ int c_parents[NJ] = {-1,0,0,0,1,2,3,4,5,6,7,8,9,9,9,12,13,14,16,17,18,19,20,21};

__device__ __forceinline__ unsigned short f2bf(float x) {
  union { float f; unsigned int u; } v; v.f = x;
  unsigned int r = v.u + 0x7fffu + ((v.u >> 16) & 1u);
  return (unsigned short)(r >> 16);
}

#define GLOBAL_AS __attribute__((address_space(1)))
#define LDS_AS __attribute__((address_space(3)))
__device__ __forceinline__ void gl_lds16(const void* g, void* l) {
  __builtin_amdgcn_global_load_lds((const GLOBAL_AS unsigned int*)g,
                                   (LDS_AS unsigned int*)l, 16, 0, 0);
}

// ---------------- Kernel A: fold J_regressor into shapedirs/template ----------------
__global__ __launch_bounds__(256) void k_regress(
    const float* __restrict__ JR, const float* __restrict__ SD,
    const float* __restrict__ VT, float* __restrict__ JS, float* __restrict__ Jt) {
  int j = blockIdx.x;
  int tid = threadIdx.x;
  float part[33];
#pragma unroll
  for (int q = 0; q < 33; q++) part[q] = 0.f;
  for (int v = tid; v < V_NUM; v += 256) {
    float jr = JR[j * V_NUM + v];
#pragma unroll
    for (int cc = 0; cc < 3; cc++) {
      part[30 + cc] += jr * VT[v * 3 + cc];
#pragma unroll
      for (int ss = 0; ss < 10; ss++)
        part[cc * 10 + ss] += jr * SD[(v * 3 + cc) * 10 + ss];
    }
  }
  __shared__ float sm[33][4];
  int lane = tid & 63, wid = tid >> 6;
#pragma unroll
  for (int q = 0; q < 33; q++) {
    float x = part[q];
    for (int off = 32; off > 0; off >>= 1) x += __shfl_down(x, off);
    if (lane == 0) sm[q][wid] = x;
  }
  __syncthreads();
  if (tid < 33) {
    float s = sm[tid][0] + sm[tid][1] + sm[tid][2] + sm[tid][3];
    if (tid < 30) JS[j * 30 + tid] = s;
    else Jt[j * 3 + (tid - 30)] = s;
  }
}

// ---------------- Kernel A2: convert A = [shapedirs | posedirs] -> bf16 [MPAD][KP] ----------------
__global__ __launch_bounds__(256) void k_convA(
    const float* __restrict__ SD, const float* __restrict__ PD,
    unsigned short* __restrict__ Abf) {
  int m = blockIdx.x;
  int k = threadIdx.x;
  float v = 0.f;
  if (m < M_DIM && k < KTOT)
    v = (k < 10) ? SD[(size_t)m * 10 + k] : PD[(size_t)m * 207 + (k - 10)];
  Abf[(size_t)m * KP + k] = f2bf(v);
}

// ---------------- Kernel A3: convert W -> bf16 fragment-ready [VPAD][32] ----------------
__global__ __launch_bounds__(256) void k_convW(
    const float* __restrict__ W, unsigned short* __restrict__ Wbf) {
  int idx = blockIdx.x * 256 + threadIdx.x;
  if (idx >= VPAD * 32) return;
  int v = idx >> 5, k = idx & 31;
  Wbf[idx] = (v < V_NUM && k < NJ) ? f2bf(W[(size_t)v * NJ + k]) : (unsigned short)0;
}

// ---------------- Kernel B: per-batch rodrigues + joints + kinematic chain ----------------
__global__ __launch_bounds__(64) void k_batch(
    const float* __restrict__ pose, const float* __restrict__ betas,
    const float* __restrict__ trans, const float* __restrict__ JS,
    const float* __restrict__ Jt, unsigned short* __restrict__ Kcb,
    unsigned short* __restrict__ GrelP, float* __restrict__ outG,
    float* __restrict__ outJtr, int B) {
  int b = blockIdx.x;
  int lane = threadIdx.x;
  __shared__ float rotS[NJ][9];
  __shared__ float jS[NJ * 3];
  __shared__ float Gs[NJ][12];
  __shared__ float GrS[NJ][12];

  if (lane < NJ) {
    float rx = pose[b * 72 + lane * 3 + 0];
    float ry = pose[b * 72 + lane * 3 + 1];
    float rz = pose[b * 72 + lane * 3 + 2];
    float a2 = rx * rx + ry * ry + rz * rz + 1e-16f;
    float ang = sqrtf(a2);
    float inv = 1.f / ang;
    float ux = rx * inv, uy = ry * inv, uz = rz * inv;
    float c = cosf(ang), s = sinf(ang), ic = 1.f - c;
    float R[9];
    R[0] = c + ic * ux * ux;      R[1] = ic * ux * uy - s * uz; R[2] = ic * ux * uz + s * uy;
    R[3] = ic * uy * ux + s * uz; R[4] = c + ic * uy * uy;      R[5] = ic * uy * uz - s * ux;
    R[6] = ic * uz * ux - s * uy; R[7] = ic * uz * uy + s * ux; R[8] = c + ic * uz * uz;
#pragma unroll
    for (int k = 0; k < 9; k++) rotS[lane][k] = R[k];
    if (lane > 0) {
#pragma unroll
      for (int k = 0; k < 9; k++) {
        float iden = (k == 0 || k == 4 || k == 8) ? 1.f : 0.f;
        Kcb[(size_t)b * KP + 10 + (lane - 1) * 9 + k] = f2bf(R[k] - iden);
      }
    }
  }
  if (lane < 10) Kcb[(size_t)b * KP + lane] = f2bf(betas[b * 10 + lane]);
  if (lane < KP - KTOT) Kcb[(size_t)b * KP + KTOT + lane] = 0;

  __syncthreads();
  for (int idx = lane; idx < 72; idx += 64) {
    float s = Jt[idx];
#pragma unroll
    for (int ss = 0; ss < 10; ss++) s += JS[idx * 10 + ss] * betas[b * 10 + ss];
    jS[idx] = s;
  }
  __syncthreads();

  if (lane == 0) {
#pragma unroll
    for (int p = 0; p < 3; p++) {
      Gs[0][p * 4 + 0] = rotS[0][p * 3 + 0];
      Gs[0][p * 4 + 1] = rotS[0][p * 3 + 1];
      Gs[0][p * 4 + 2] = rotS[0][p * 3 + 2];
      Gs[0][p * 4 + 3] = jS[p];
    }
    for (int i = 1; i < NJ; i++) {
      int par = c_parents[i];
      float t0 = jS[i * 3 + 0] - jS[par * 3 + 0];
      float t1 = jS[i * 3 + 1] - jS[par * 3 + 1];
      float t2 = jS[i * 3 + 2] - jS[par * 3 + 2];
#pragma unroll
      for (int p = 0; p < 3; p++) {
        float rp0 = Gs[par][p * 4 + 0], rp1 = Gs[par][p * 4 + 1], rp2 = Gs[par][p * 4 + 2];
#pragma unroll
        for (int q = 0; q < 3; q++) {
          Gs[i][p * 4 + q] = rp0 * rotS[i][0 * 3 + q] + rp1 * rotS[i][1 * 3 + q] + rp2 * rotS[i][2 * 3 + q];
        }
        Gs[i][p * 4 + 3] = rp0 * t0 + rp1 * t1 + rp2 * t2 + Gs[par][p * 4 + 3];
      }
    }
    for (int i = 0; i < NJ; i++) {
      float jx = jS[i * 3 + 0], jy = jS[i * 3 + 1], jz = jS[i * 3 + 2];
#pragma unroll
      for (int p = 0; p < 3; p++) {
        float g0 = Gs[i][p * 4 + 0], g1 = Gs[i][p * 4 + 1], g2 = Gs[i][p * 4 + 2];
        GrS[i][p * 4 + 0] = g0;
        GrS[i][p * 4 + 1] = g1;
        GrS[i][p * 4 + 2] = g2;
        GrS[i][p * 4 + 3] = Gs[i][p * 4 + 3] - (g0 * jx + g1 * jy + g2 * jz);
      }
    }
  }
  __syncthreads();

  for (int idx = lane; idx < NJ * 16; idx += 64) {
    int jj = idx >> 4, rc = idx & 15, p = rc >> 2, q = rc & 3;
    float val = (p < 3) ? Gs[jj][p * 4 + q] : ((q == 3) ? 1.f : 0.f);
    outG[(size_t)b * NJ * 16 + idx] = val;
  }
  for (int idx = lane; idx < NJ * 3; idx += 64) {
    int jj = idx / 3, p = idx % 3;
    outJtr[(size_t)b * NJ * 3 + idx] = Gs[jj][p * 4 + 3] + trans[b * 3 + p];
  }
  // GrelT bf16 panel: [c=0..15][j=0..39], zeros outside c<12, j<24
  for (int idx = lane; idx < 16 * 40; idx += 64) {
    int c = idx / 40, j = idx % 40;
    GrelP[(size_t)b * 640 + idx] = (c < 12 && j < NJ) ? f2bf(GrS[j][c]) : (unsigned short)0;
  }
}

// ---------------- Kernel C: MFMA GEMM  D[m][b]; LDS-staged coalesced epilogue ----------------
// acc[fi][fj]: D row = m (4 consecutive per lane), col = b (lane&15).
// Epilogue: 4 passes (one per fj); stage 32 b-rows x 128 m into LDS, then write
// 128B-contiguous float4 runs per b-row for both VP and NK.
__global__ __launch_bounds__(256) void k_pose_mfma(
    const unsigned short* __restrict__ Kcb, const unsigned short* __restrict__ Abf,
    const float* __restrict__ VT,
    float* __restrict__ outVP, float* __restrict__ outNK, int B) {
  __shared__ char ldsraw[32768];           // At(16K)+Bt(16K); reused as stage (16.9K)
  __shared__ float vtS[128];
  unsigned short* At = (unsigned short*)ldsraw;        // Kcb rows (b-local)
  unsigned short* Bt = At + 128 * 64;                  // Abf rows (m-local)
  float* stage = (float*)ldsraw;                       // [32][132] f32

  const int tid = threadIdx.x;
  const int lane = tid & 63;
  const int w = tid >> 6;
  const int wr = w >> 1, wc = w & 1;       // wr -> m half, wc -> b half
  const int b0 = blockIdx.y * 128;
  const int m0 = blockIdx.x * 128;

  if (tid < 128) vtS[tid] = (m0 + tid < M_DIM) ? VT[m0 + tid] : 0.f;

  f32x4 acc[4][4];
#pragma unroll
  for (int i = 0; i < 4; i++)
#pragma unroll
    for (int j = 0; j < 4; j++) acc[i][j] = (f32x4){0.f, 0.f, 0.f, 0.f};

  int Lrow[4], Lkb[4];
#pragma unroll
  for (int i = 0; i < 4; i++) {
    int L = w * 4096 + i * 1024 + lane * 16;
    int row = L >> 7;
    int kb = (L & 127) ^ ((row & 7) << 4);
    Lrow[i] = row;
    Lkb[i] = kb >> 1;
  }

  for (int kt = 0; kt < KP / 64; ++kt) {
#pragma unroll
    for (int i = 0; i < 4; i++) {
      const unsigned short* gA = Kcb + (size_t)(b0 + Lrow[i]) * KP + kt * 64 + Lkb[i];
      gl_lds16(gA, (char*)At + w * 4096 + i * 1024);
    }
#pragma unroll
    for (int i = 0; i < 4; i++) {
      const unsigned short* gB = Abf + (size_t)(m0 + Lrow[i]) * KP + kt * 64 + Lkb[i];
      gl_lds16(gB, (char*)Bt + w * 4096 + i * 1024);
    }
    __syncthreads();

#pragma unroll
    for (int h = 0; h < 2; ++h) {
      bf16x8 fm[4], fb[4];
#pragma unroll
      for (int fi = 0; fi < 4; fi++) {
        int row = wr * 64 + fi * 16 + (lane & 15);
        int byte = (row << 7) + ((h * 64 + ((lane >> 4) << 4)) ^ ((row & 7) << 4));
        fm[fi] = *(const bf16x8*)((const char*)Bt + byte);
      }
#pragma unroll
      for (int fj = 0; fj < 4; fj++) {
        int row = wc * 64 + fj * 16 + (lane & 15);
        int byte = (row << 7) + ((h * 64 + ((lane >> 4) << 4)) ^ ((row & 7) << 4));
        fb[fj] = *(const bf16x8*)((const char*)At + byte);
      }
#pragma unroll
      for (int fi = 0; fi < 4; fi++)
#pragma unroll
        for (int fj = 0; fj < 4; fj++)
          acc[fi][fj] = __builtin_amdgcn_mfma_f32_16x16x32_bf16(fm[fi], fb[fj], acc[fi][fj], 0, 0, 0);
    }
    __syncthreads();
  }

  // LDS-staged epilogue: pass pp = fj. Stage rows = wc*16 + (lane&15).
#pragma unroll
  for (int pp = 0; pp < 4; pp++) {
    __syncthreads();   // previous pass reads done (first: main loop done)
    {
      int rowIdx = wc * 16 + (lane & 15);
#pragma unroll
      for (int fi = 0; fi < 4; fi++) {
        int ml = wr * 64 + fi * 16 + ((lane >> 4) << 2);
        *(f32x4*)&stage[rowIdx * 132 + ml] = acc[fi][pp];
      }
    }
    __syncthreads();
    int row = tid >> 3;                       // 0..31
    int brow = ((row >> 4) * 64) + pp * 16 + (row & 15);
    size_t gb = (size_t)(b0 + brow) * M_DIM;
#pragma unroll
    for (int i = 0; i < 4; i++) {
      int col4 = (tid & 7) + 8 * i;           // 0..31
      int mg = m0 + col4 * 4;
      f32x4 v = *(f32x4*)&stage[row * 132 + col4 * 4];
      f32x4 vt = *(f32x4*)&vtS[col4 * 4];
      v = v + vt;
      if (mg + 3 < M_DIM) {
        *(f32x4*)(outVP + gb + mg) = v;
        *(f32x4*)(outNK + gb + mg) = v;
      } else {
#pragma unroll
        for (int r = 0; r < 4; r++) {
          if (mg + r < M_DIM) {
            outVP[gb + mg + r] = v[r];
            outNK[gb + mg + r] = v[r];
          }
        }
      }
    }
  }
}

// ---------------- Kernel D: MFMA skinning, software-pipelined ----------------
// Wave owns 64 verts; loops 8 batches. Next batch's Grel fragment + NK x-vector
// are issued BEFORE the LDS drain so their latency hides under the current apply.
__global__ __launch_bounds__(256) void k_skin4(
    const float* __restrict__ NK, const unsigned short* __restrict__ Wbf,
    const unsigned short* __restrict__ GrelP, const float* __restrict__ trans,
    float* __restrict__ outVerts, int B) {
  __shared__ float Tl[4][64 * 13];
  const int tid = threadIdx.x;
  const int lane = tid & 63;
  const int w = tid >> 6;
  const int vl16 = lane & 15;
  const int p = lane >> 4;        // c-row group (3 = zero rows)
  const int kb = p * 8;           // k-base of this lane's fragment
  const int vbase = blockIdx.x * 256 + w * 64;
  const int b0 = blockIdx.y * 8;
  const int vg = vbase + lane;    // this lane's owned vert
  const bool vok = vg < V_NUM;

  // W B-fragments, reused across 8 batches (rows = verts)
  bf16x8 wf[4];
#pragma unroll
  for (int sub = 0; sub < 4; sub++)
    wf[sub] = *(const bf16x8*)(Wbf + (size_t)(vbase + sub * 16 + vl16) * 32 + kb);

  float* myT = Tl[w];

  // prologue: batch b0 fragment + x-vector
  bf16x8 af = *(const bf16x8*)(GrelP + (size_t)b0 * 640 + vl16 * 40 + kb);
  float xc0 = 0.f, xc1 = 0.f, xc2 = 0.f;
  if (vok) {
    const float* xp = NK + (size_t)b0 * M_DIM + (size_t)vg * 3;
    xc0 = xp[0]; xc1 = xp[1]; xc2 = xp[2];
  }

#pragma unroll
  for (int bi = 0; bi < 8; bi++) {
    int b = b0 + bi;
    f32x4 acc[4];
#pragma unroll
    for (int sub = 0; sub < 4; sub++) {
      f32x4 z = (f32x4){0.f, 0.f, 0.f, 0.f};
      acc[sub] = __builtin_amdgcn_mfma_f32_16x16x32_bf16(af, wf[sub], z, 0, 0, 0);
    }
    // scatter T to LDS: T[vert][c], c = p*4 + r
    if (p < 3) {
#pragma unroll
      for (int sub = 0; sub < 4; sub++) {
        int vi = sub * 16 + vl16;
#pragma unroll
        for (int r = 0; r < 4; r++)
          myT[vi * 13 + p * 4 + r] = acc[sub][r];
      }
    }
    // issue next iteration's loads (independent) so they fly during drain+apply
    bf16x8 af_n = af;
    float xn0 = 0.f, xn1 = 0.f, xn2 = 0.f;
    if (bi < 7) {
      af_n = *(const bf16x8*)(GrelP + (size_t)(b + 1) * 640 + vl16 * 40 + kb);
      if (vok) {
        const float* xp = NK + (size_t)(b + 1) * M_DIM + (size_t)vg * 3;
        xn0 = xp[0]; xn1 = xp[1]; xn2 = xp[2];
      }
    }
    asm volatile("s_waitcnt lgkmcnt(0)" ::: "memory");
    __builtin_amdgcn_sched_barrier(0);
    // per-lane vert apply (coalesced)
    if (vok) {
      float t[12];
#pragma unroll
      for (int c = 0; c < 12; c++) t[c] = myT[lane * 13 + c];
      float* op = outVerts + (size_t)b * M_DIM + (size_t)vg * 3;
      op[0] = t[0] * xc0 + t[1] * xc1 + t[2] * xc2 + t[3] + trans[b * 3 + 0];
      op[1] = t[4] * xc0 + t[5] * xc1 + t[6] * xc2 + t[7] + trans[b * 3 + 1];
      op[2] = t[8] * xc0 + t[9] * xc1 + t[10] * xc2 + t[11] + trans[b * 3 + 2];
    }
    af = af_n; xc0 = xn0; xc1 = xn1; xc2 = xn2;
  }
}

extern "C" void kernel_launch(void* const* d_in, const int* in_sizes, int n_in,
                              void* d_out, int out_size, void* d_ws, size_t ws_size,
                              hipStream_t stream) {
  const float* pose  = (const float*)d_in[0];
  const float* betas = (const float*)d_in[1];
  const float* trans = (const float*)d_in[2];
  const float* vt    = (const float*)d_in[3];
  const float* sd    = (const float*)d_in[4];
  const float* pd    = (const float*)d_in[5];
  const float* jreg  = (const float*)d_in[6];
  const float* wgt   = (const float*)d_in[7];
  int B = in_sizes[0] / 72;

  float* out = (float*)d_out;
  size_t nvb = (size_t)B * M_DIM;
  float* o_verts = out;
  float* o_jtr   = o_verts + nvb;
  float* o_vp    = o_jtr + (size_t)B * NJ * 3;
  float* o_nk    = o_vp + nvb;
  float* o_G     = o_nk + nvb;

  char* wsb = (char*)d_ws;
  float* JS = (float*)wsb;                          // 720 f32
  float* Jt = JS + 720;                             // 72 f32
  size_t off = (720 + 72) * 4;                      // 3168 B (16-aligned)
  unsigned short* Kcb   = (unsigned short*)(wsb + off);                       // B*KP
  unsigned short* Abf   = (unsigned short*)(wsb + off + (size_t)B * KP * 2);  // MPAD*KP
  unsigned short* GrelP = Abf + (size_t)MPAD * KP;                            // B*640
  unsigned short* Wbf   = GrelP + (size_t)B * 640;                            // VPAD*32

  k_regress<<<24, 256, 0, stream>>>(jreg, sd, vt, JS, Jt);
  k_convA<<<MPAD, 256, 0, stream>>>(sd, pd, Abf);
  k_convW<<<(VPAD * 32 + 255) / 256, 256, 0, stream>>>(wgt, Wbf);
  k_batch<<<B, 64, 0, stream>>>(pose, betas, trans, JS, Jt, Kcb, GrelP, o_G, o_jtr, B);
  dim3 gC(MPAD / 128, B / 128);
  k_pose_mfma<<<gC, 256, 0, stream>>>(Kcb, Abf, vt, o_vp, o_nk, B);
  dim3 gD(VPAD / 256, B / 8);
  k_skin4<<<gD, 256, 0, stream>>>(o_nk, Wbf, GrelP, trans, o_verts, B);
}

// Round 7
// 151.657 us; speedup vs baseline: 1.3174x; 1.0111x over previous
//
#include <hip/hip_runtime.h>
#include <math.h>

#define V_NUM 6890
#define NJ 24
#define KTOT 217            // 10 betas + 207 pose_map
#define KP 256              // padded K (multiple of 64)
#define M_DIM (V_NUM * 3)   // 20670
#define MPAD 20736          // 162 * 128
#define VPAD 6912           // 27 * 256

typedef __attribute__((ext_vector_type(8))) short bf16x8;
typedef __attribute__((ext_vector_type(4))) float f32x4;

__constant__ int c_parents[NJ] = {-1,0,0,0,1,2,3,4,5,6,7,8,9,9,9,12,13,14,16,17,18,19,20,21};

__device__ __forceinline__ unsigned short f2bf(float x) {
  union { float f; unsigned int u; } v; v.f = x;
  unsigned int r = v.u + 0x7fffu + ((v.u >> 16) & 1u);
  return (unsigned short)(r >> 16);
}

#define GLOBAL_AS __attribute__((address_space(1)))
#define LDS_AS __attribute__((address_space(3)))
__device__ __forceinline__ void gl_lds16(const void* g, void* l) {
  __builtin_amdgcn_global_load_lds((const GLOBAL_AS unsigned int*)g,
                                   (LDS_AS unsigned int*)l, 16, 0, 0);
}

// ---------------- Kernel A: fold J_regressor into shapedirs/template ----------------
__global__ __launch_bounds__(256) void k_regress(
    const float* __restrict__ JR, const float* __restrict__ SD,
    const float* __restrict__ VT, float* __restrict__ JS, float* __restrict__ Jt) {
  int j = blockIdx.x;
  int tid = threadIdx.x;
  float part[33];
#pragma unroll
  for (int q = 0; q < 33; q++) part[q] = 0.f;
  for (int v = tid; v < V_NUM; v += 256) {
    float jr = JR[j * V_NUM + v];
#pragma unroll
    for (int cc = 0; cc < 3; cc++) {
      part[30 + cc] += jr * VT[v * 3 + cc];
#pragma unroll
      for (int ss = 0; ss < 10; ss++)
        part[cc * 10 + ss] += jr * SD[(v * 3 + cc) * 10 + ss];
    }
  }
  __shared__ float sm[33][4];
  int lane = tid & 63, wid = tid >> 6;
#pragma unroll
  for (int q = 0; q < 33; q++) {
    float x = part[q];
    for (int off = 32; off > 0; off >>= 1) x += __shfl_down(x, off);
    if (lane == 0) sm[q][wid] = x;
  }
  __syncthreads();
  if (tid < 33) {
    float s = sm[tid][0] + sm[tid][1] + sm[tid][2] + sm[tid][3];
    if (tid < 30) JS[j * 30 + tid] = s;
    else Jt[j * 3 + (tid - 30)] = s;
  }
}

// ---------------- Kernel A2: convert A = [shapedirs | posedirs] -> bf16 [MPAD][KP] ----------------
__global__ __launch_bounds__(256) void k_convA(
    const float* __restrict__ SD, const float* __restrict__ PD,
    unsigned short* __restrict__ Abf) {
  int m = blockIdx.x;
  int k = threadIdx.x;
  float v = 0.f;
  if (m < M_DIM && k < KTOT)
    v = (k < 10) ? SD[(size_t)m * 10 + k] : PD[(size_t)m * 207 + (k - 10)];
  Abf[(size_t)m * KP + k] = f2bf(v);
}

// ---------------- Kernel A3: convert W -> bf16 fragment-ready [VPAD][32] ----------------
__global__ __launch_bounds__(256) void k_convW(
    const float* __restrict__ W, unsigned short* __restrict__ Wbf) {
  int idx = blockIdx.x * 256 + threadIdx.x;
  if (idx >= VPAD * 32) return;
  int v = idx >> 5, k = idx & 31;
  Wbf[idx] = (v < V_NUM && k < NJ) ? f2bf(W[(size_t)v * NJ + k]) : (unsigned short)0;
}

// ---------------- Kernel B: per-batch rodrigues + joints + kinematic chain ----------------
__global__ __launch_bounds__(64) void k_batch(
    const float* __restrict__ pose, const float* __restrict__ betas,
    const float* __restrict__ trans, const float* __restrict__ JS,
    const float* __restrict__ Jt, unsigned short* __restrict__ Kcb,
    unsigned short* __restrict__ GrelP, float* __restrict__ outG,
    float* __restrict__ outJtr, int B) {
  int b = blockIdx.x;
  int lane = threadIdx.x;
  __shared__ float rotS[NJ][9];
  __shared__ float jS[NJ * 3];
  __shared__ float Gs[NJ][12];
  __shared__ float GrS[NJ][12];

  if (lane < NJ) {
    float rx = pose[b * 72 + lane * 3 + 0];
    float ry = pose[b * 72 + lane * 3 + 1];
    float rz = pose[b * 72 + lane * 3 + 2];
    float a2 = rx * rx + ry * ry + rz * rz + 1e-16f;
    float ang = sqrtf(a2);
    float inv = 1.f / ang;
    float ux = rx * inv, uy = ry * inv, uz = rz * inv;
    float c = cosf(ang), s = sinf(ang), ic = 1.f - c;
    float R[9];
    R[0] = c + ic * ux * ux;      R[1] = ic * ux * uy - s * uz; R[2] = ic * ux * uz + s * uy;
    R[3] = ic * uy * ux + s * uz; R[4] = c + ic * uy * uy;      R[5] = ic * uy * uz - s * ux;
    R[6] = ic * uz * ux - s * uy; R[7] = ic * uz * uy + s * ux; R[8] = c + ic * uz * uz;
#pragma unroll
    for (int k = 0; k < 9; k++) rotS[lane][k] = R[k];
    if (lane > 0) {
#pragma unroll
      for (int k = 0; k < 9; k++) {
        float iden = (k == 0 || k == 4 || k == 8) ? 1.f : 0.f;
        Kcb[(size_t)b * KP + 10 + (lane - 1) * 9 + k] = f2bf(R[k] - iden);
      }
    }
  }
  if (lane < 10) Kcb[(size_t)b * KP + lane] = f2bf(betas[b * 10 + lane]);
  if (lane < KP - KTOT) Kcb[(size_t)b * KP + KTOT + lane] = 0;

  __syncthreads();
  for (int idx = lane; idx < 72; idx += 64) {
    float s = Jt[idx];
#pragma unroll
    for (int ss = 0; ss < 10; ss++) s += JS[idx * 10 + ss] * betas[b * 10 + ss];
    jS[idx] = s;
  }
  __syncthreads();

  if (lane == 0) {
#pragma unroll
    for (int p = 0; p < 3; p++) {
      Gs[0][p * 4 + 0] = rotS[0][p * 3 + 0];
      Gs[0][p * 4 + 1] = rotS[0][p * 3 + 1];
      Gs[0][p * 4 + 2] = rotS[0][p * 3 + 2];
      Gs[0][p * 4 + 3] = jS[p];
    }
    for (int i = 1; i < NJ; i++) {
      int par = c_parents[i];
      float t0 = jS[i * 3 + 0] - jS[par * 3 + 0];
      float t1 = jS[i * 3 + 1] - jS[par * 3 + 1];
      float t2 = jS[i * 3 + 2] - jS[par * 3 + 2];
#pragma unroll
      for (int p = 0; p < 3; p++) {
        float rp0 = Gs[par][p * 4 + 0], rp1 = Gs[par][p * 4 + 1], rp2 = Gs[par][p * 4 + 2];
#pragma unroll
        for (int q = 0; q < 3; q++) {
          Gs[i][p * 4 + q] = rp0 * rotS[i][0 * 3 + q] + rp1 * rotS[i][1 * 3 + q] + rp2 * rotS[i][2 * 3 + q];
        }
        Gs[i][p * 4 + 3] = rp0 * t0 + rp1 * t1 + rp2 * t2 + Gs[par][p * 4 + 3];
      }
    }
    for (int i = 0; i < NJ; i++) {
      float jx = jS[i * 3 + 0], jy = jS[i * 3 + 1], jz = jS[i * 3 + 2];
#pragma unroll
      for (int p = 0; p < 3; p++) {
        float g0 = Gs[i][p * 4 + 0], g1 = Gs[i][p * 4 + 1], g2 = Gs[i][p * 4 + 2];
        GrS[i][p * 4 + 0] = g0;
        GrS[i][p * 4 + 1] = g1;
        GrS[i][p * 4 + 2] = g2;
        GrS[i][p * 4 + 3] = Gs[i][p * 4 + 3] - (g0 * jx + g1 * jy + g2 * jz);
      }
    }
  }
  __syncthreads();

  for (int idx = lane; idx < NJ * 16; idx += 64) {
    int jj = idx >> 4, rc = idx & 15, p = rc >> 2, q = rc & 3;
    float val = (p < 3) ? Gs[jj][p * 4 + q] : ((q == 3) ? 1.f : 0.f);
    outG[(size_t)b * NJ * 16 + idx] = val;
  }
  for (int idx = lane; idx < NJ * 3; idx += 64) {
    int jj = idx / 3, p = idx % 3;
    outJtr[(size_t)b * NJ * 3 + idx] = Gs[jj][p * 4 + 3] + trans[b * 3 + p];
  }
  // GrelT bf16 panel: [c=0..15][j=0..39], zeros outside c<12, j<24
  for (int idx = lane; idx < 16 * 40; idx += 64) {
    int c = idx / 40, j = idx % 40;
    GrelP[(size_t)b * 640 + idx] = (c < 12 && j < NJ) ? f2bf(GrS[j][c]) : (unsigned short)0;
  }
}

// ---------------- Kernel C: MFMA GEMM  D[m][b]; writes ONLY v_posed (VP) ----------------
// acc[fi][fj]: D row = m (4 consecutive per lane), col = b (lane&15).
// Epilogue: 4 passes; stage 32 b-rows x 128 m into LDS, write 128B float4 runs.
__global__ __launch_bounds__(256) void k_pose_mfma(
    const unsigned short* __restrict__ Kcb, const unsigned short* __restrict__ Abf,
    const float* __restrict__ VT, float* __restrict__ outVP, int B) {
  __shared__ char ldsraw[32768];           // At(16K)+Bt(16K); reused as stage (16.9K)
  __shared__ float vtS[128];
  unsigned short* At = (unsigned short*)ldsraw;        // Kcb rows (b-local)
  unsigned short* Bt = At + 128 * 64;                  // Abf rows (m-local)
  float* stage = (float*)ldsraw;                       // [32][132] f32

  const int tid = threadIdx.x;
  const int lane = tid & 63;
  const int w = tid >> 6;
  const int wr = w >> 1, wc = w & 1;       // wr -> m half, wc -> b half
  const int b0 = blockIdx.y * 128;
  const int m0 = blockIdx.x * 128;

  if (tid < 128) vtS[tid] = (m0 + tid < M_DIM) ? VT[m0 + tid] : 0.f;

  f32x4 acc[4][4];
#pragma unroll
  for (int i = 0; i < 4; i++)
#pragma unroll
    for (int j = 0; j < 4; j++) acc[i][j] = (f32x4){0.f, 0.f, 0.f, 0.f};

  int Lrow[4], Lkb[4];
#pragma unroll
  for (int i = 0; i < 4; i++) {
    int L = w * 4096 + i * 1024 + lane * 16;
    int row = L >> 7;
    int kb = (L & 127) ^ ((row & 7) << 4);
    Lrow[i] = row;
    Lkb[i] = kb >> 1;
  }

  for (int kt = 0; kt < KP / 64; ++kt) {
#pragma unroll
    for (int i = 0; i < 4; i++) {
      const unsigned short* gA = Kcb + (size_t)(b0 + Lrow[i]) * KP + kt * 64 + Lkb[i];
      gl_lds16(gA, (char*)At + w * 4096 + i * 1024);
    }
#pragma unroll
    for (int i = 0; i < 4; i++) {
      const unsigned short* gB = Abf + (size_t)(m0 + Lrow[i]) * KP + kt * 64 + Lkb[i];
      gl_lds16(gB, (char*)Bt + w * 4096 + i * 1024);
    }
    __syncthreads();

#pragma unroll
    for (int h = 0; h < 2; ++h) {
      bf16x8 fm[4], fb[4];
#pragma unroll
      for (int fi = 0; fi < 4; fi++) {
        int row = wr * 64 + fi * 16 + (lane & 15);
        int byte = (row << 7) + ((h * 64 + ((lane >> 4) << 4)) ^ ((row & 7) << 4));
        fm[fi] = *(const bf16x8*)((const char*)Bt + byte);
      }
#pragma unroll
      for (int fj = 0; fj < 4; fj++) {
        int row = wc * 64 + fj * 16 + (lane & 15);
        int byte = (row << 7) + ((h * 64 + ((lane >> 4) << 4)) ^ ((row & 7) << 4));
        fb[fj] = *(const bf16x8*)((const char*)At + byte);
      }
#pragma unroll
      for (int fi = 0; fi < 4; fi++)
#pragma unroll
        for (int fj = 0; fj < 4; fj++)
          acc[fi][fj] = __builtin_amdgcn_mfma_f32_16x16x32_bf16(fm[fi], fb[fj], acc[fi][fj], 0, 0, 0);
    }
    __syncthreads();
  }

  // LDS-staged epilogue: pass pp = fj. Stage rows = wc*16 + (lane&15).
#pragma unroll
  for (int pp = 0; pp < 4; pp++) {
    __syncthreads();
    {
      int rowIdx = wc * 16 + (lane & 15);
#pragma unroll
      for (int fi = 0; fi < 4; fi++) {
        int ml = wr * 64 + fi * 16 + ((lane >> 4) << 2);
        *(f32x4*)&stage[rowIdx * 132 + ml] = acc[fi][pp];
      }
    }
    __syncthreads();
    int row = tid >> 3;                       // 0..31
    int brow = ((row >> 4) * 64) + pp * 16 + (row & 15);
    size_t gb = (size_t)(b0 + brow) * M_DIM;
#pragma unroll
    for (int i = 0; i < 4; i++) {
      int col4 = (tid & 7) + 8 * i;           // 0..31
      int mg = m0 + col4 * 4;
      f32x4 v = *(f32x4*)&stage[row * 132 + col4 * 4];
      f32x4 vt = *(f32x4*)&vtS[col4 * 4];
      v = v + vt;
      if (mg + 3 < M_DIM) {
        *(f32x4*)(outVP + gb + mg) = v;
      } else {
#pragma unroll
        for (int r = 0; r < 4; r++)
          if (mg + r < M_DIM) outVP[gb + mg + r] = v[r];
      }
    }
  }
}

// ---------------- Kernel D: MFMA skinning; reads VP (L3-hot), writes NK copy + verts ----------------
// Wave owns 64 verts; loops 8 batches, software-pipelined (next batch's Grel frag +
// x-vector issued before the LDS drain). NK = bitwise copy of VP (naked == v_posed).
__global__ __launch_bounds__(256) void k_skin5(
    const float* __restrict__ VP, const unsigned short* __restrict__ Wbf,
    const unsigned short* __restrict__ GrelP, const float* __restrict__ trans,
    float* __restrict__ outNK, float* __restrict__ outVerts, int B) {
  __shared__ float Tl[4][64 * 13];
  const int tid = threadIdx.x;
  const int lane = tid & 63;
  const int w = tid >> 6;
  const int vl16 = lane & 15;
  const int p = lane >> 4;        // c-row group (3 = zero rows)
  const int kb = p * 8;           // k-base of this lane's fragment
  const int vbase = blockIdx.x * 256 + w * 64;
  const int b0 = blockIdx.y * 8;
  const int vg = vbase + lane;    // this lane's owned vert
  const bool vok = vg < V_NUM;

  // W B-fragments, reused across 8 batches (rows = verts)
  bf16x8 wf[4];
#pragma unroll
  for (int sub = 0; sub < 4; sub++)
    wf[sub] = *(const bf16x8*)(Wbf + (size_t)(vbase + sub * 16 + vl16) * 32 + kb);

  float* myT = Tl[w];

  // prologue: batch b0 fragment + x-vector
  bf16x8 af = *(const bf16x8*)(GrelP + (size_t)b0 * 640 + vl16 * 40 + kb);
  float xc0 = 0.f, xc1 = 0.f, xc2 = 0.f;
  if (vok) {
    const float* xp = VP + (size_t)b0 * M_DIM + (size_t)vg * 3;
    xc0 = xp[0]; xc1 = xp[1]; xc2 = xp[2];
  }

#pragma unroll
  for (int bi = 0; bi < 8; bi++) {
    int b = b0 + bi;
    f32x4 acc[4];
#pragma unroll
    for (int sub = 0; sub < 4; sub++) {
      f32x4 z = (f32x4){0.f, 0.f, 0.f, 0.f};
      acc[sub] = __builtin_amdgcn_mfma_f32_16x16x32_bf16(af, wf[sub], z, 0, 0, 0);
    }
    // scatter T to LDS: T[vert][c], c = p*4 + r
    if (p < 3) {
#pragma unroll
      for (int sub = 0; sub < 4; sub++) {
        int vi = sub * 16 + vl16;
#pragma unroll
        for (int r = 0; r < 4; r++)
          myT[vi * 13 + p * 4 + r] = acc[sub][r];
      }
    }
    // issue next iteration's loads (independent) so they fly during drain+apply
    bf16x8 af_n = af;
    float xn0 = 0.f, xn1 = 0.f, xn2 = 0.f;
    if (bi < 7) {
      af_n = *(const bf16x8*)(GrelP + (size_t)(b + 1) * 640 + vl16 * 40 + kb);
      if (vok) {
        const float* xp = VP + (size_t)(b + 1) * M_DIM + (size_t)vg * 3;
        xn0 = xp[0]; xn1 = xp[1]; xn2 = xp[2];
      }
    }
    asm volatile("s_waitcnt lgkmcnt(0)" ::: "memory");
    __builtin_amdgcn_sched_barrier(0);
    // per-lane vert apply (coalesced); also emit NK copy
    if (vok) {
      float t[12];
#pragma unroll
      for (int c = 0; c < 12; c++) t[c] = myT[lane * 13 + c];
      size_t base = (size_t)b * M_DIM + (size_t)vg * 3;
      float* onk = outNK + base;
      onk[0] = xc0; onk[1] = xc1; onk[2] = xc2;
      float* op = outVerts + base;
      op[0] = t[0] * xc0 + t[1] * xc1 + t[2] * xc2 + t[3] + trans[b * 3 + 0];
      op[1] = t[4] * xc0 + t[5] * xc1 + t[6] * xc2 + t[7] + trans[b * 3 + 1];
      op[2] = t[8] * xc0 + t[9] * xc1 + t[10] * xc2 + t[11] + trans[b * 3 + 2];
    }
    af = af_n; xc0 = xn0; xc1 = xn1; xc2 = xn2;
  }
}

extern "C" void kernel_launch(void* const* d_in, const int* in_sizes, int n_in,
                              void* d_out, int out_size, void* d_ws, size_t ws_size,
                              hipStream_t stream) {
  const float* pose  = (const float*)d_in[0];
  const float* betas = (const float*)d_in[1];
  const float* trans = (const float*)d_in[2];
  const float* vt    = (const float*)d_in[3];
  const float* sd    = (const float*)d_in[4];
  const float* pd    = (const float*)d_in[5];
  const float* jreg  = (const float*)d_in[6];
  const float* wgt   = (const float*)d_in[7];
  int B = in_sizes[0] / 72;

  float* out = (float*)d_out;
  size_t nvb = (size_t)B * M_DIM;
  float* o_verts = out;
  float* o_jtr   = o_verts + nvb;
  float* o_vp    = o_jtr + (size_t)B * NJ * 3;
  float* o_nk    = o_vp + nvb;
  float* o_G     = o_nk + nvb;

  char* wsb = (char*)d_ws;
  float* JS = (float*)wsb;                          // 720 f32
  float* Jt = JS + 720;                             // 72 f32
  size_t off = (720 + 72) * 4;                      // 3168 B (16-aligned)
  unsigned short* Kcb   = (unsigned short*)(wsb + off);                       // B*KP
  unsigned short* Abf   = (unsigned short*)(wsb + off + (size_t)B * KP * 2);  // MPAD*KP
  unsigned short* GrelP = Abf + (size_t)MPAD * KP;                            // B*640
  unsigned short* Wbf   = GrelP + (size_t)B * 640;                            // VPAD*32

  k_regress<<<24, 256, 0, stream>>>(jreg, sd, vt, JS, Jt);
  k_convA<<<MPAD, 256, 0, stream>>>(sd, pd, Abf);
  k_convW<<<(VPAD * 32 + 255) / 256, 256, 0, stream>>>(wgt, Wbf);
  k_batch<<<B, 64, 0, stream>>>(pose, betas, trans, JS, Jt, Kcb, GrelP, o_G, o_jtr, B);
  dim3 gC(MPAD / 128, B / 128);
  k_pose_mfma<<<gC, 256, 0, stream>>>(Kcb, Abf, vt, o_vp, B);
  dim3 gD(VPAD / 256, B / 8);
  k_skin5<<<gD, 256, 0, stream>>>(o_vp, Wbf, GrelP, trans, o_nk, o_verts, B);
}

// Round 8
// 151.429 us; speedup vs baseline: 1.3194x; 1.0015x over previous
//
#include <hip/hip_runtime.h>
#include <math.h>

#define V_NUM 6890
#define NJ 24
#define KTOT 217            // 10 betas + 207 pose_map
#define KP 256              // padded K (multiple of 64)
#define M_DIM (V_NUM * 3)   // 20670
#define MPAD 20736          // 162 * 128
#define VPAD 6912           // 27 * 256

typedef __attribute__((ext_vector_type(8))) short bf16x8;
typedef __attribute__((ext_vector_type(4))) float f32x4;

__constant__ int c_parents[NJ] = {-1,0,0,0,1,2,3,4,5,6,7,8,9,9,9,12,13,14,16,17,18,19,20,21};

__device__ __forceinline__ unsigned short f2bf(float x) {
  union { float f; unsigned int u; } v; v.f = x;
  unsigned int r = v.u + 0x7fffu + ((v.u >> 16) & 1u);
  return (unsigned short)(r >> 16);
}

#define GLOBAL_AS __attribute__((address_space(1)))
#define LDS_AS __attribute__((address_space(3)))
__device__ __forceinline__ void gl_lds16(const void* g, void* l) {
  __builtin_amdgcn_global_load_lds((const GLOBAL_AS unsigned int*)g,
                                   (LDS_AS unsigned int*)l, 16, 0, 0);
}

// ---------------- Kernel A: fold J_regressor into shapedirs/template ----------------
__global__ __launch_bounds__(256) void k_regress(
    const float* __restrict__ JR, const float* __restrict__ SD,
    const float* __restrict__ VT, float* __restrict__ JS, float* __restrict__ Jt) {
  int j = blockIdx.x;
  int tid = threadIdx.x;
  float part[33];
#pragma unroll
  for (int q = 0; q < 33; q++) part[q] = 0.f;
  for (int v = tid; v < V_NUM; v += 256) {
    float jr = JR[j * V_NUM + v];
#pragma unroll
    for (int cc = 0; cc < 3; cc++) {
      part[30 + cc] += jr * VT[v * 3 + cc];
#pragma unroll
      for (int ss = 0; ss < 10; ss++)
        part[cc * 10 + ss] += jr * SD[(v * 3 + cc) * 10 + ss];
    }
  }
  __shared__ float sm[33][4];
  int lane = tid & 63, wid = tid >> 6;
#pragma unroll
  for (int q = 0; q < 33; q++) {
    float x = part[q];
    for (int off = 32; off > 0; off >>= 1) x += __shfl_down(x, off);
    if (lane == 0) sm[q][wid] = x;
  }
  __syncthreads();
  if (tid < 33) {
    float s = sm[tid][0] + sm[tid][1] + sm[tid][2] + sm[tid][3];
    if (tid < 30) JS[j * 30 + tid] = s;
    else Jt[j * 3 + (tid - 30)] = s;
  }
}

// ---------------- Kernel A2: convert A -> bf16 [MPAD][KP]  AND  W -> bf16 [VPAD][32] ----------------
__global__ __launch_bounds__(256) void k_conv(
    const float* __restrict__ SD, const float* __restrict__ PD,
    const float* __restrict__ W,
    unsigned short* __restrict__ Abf, unsigned short* __restrict__ Wbf) {
  int bid = blockIdx.x;
  int tid = threadIdx.x;
  if (bid < MPAD) {
    int m = bid, k = tid;
    float v = 0.f;
    if (m < M_DIM && k < KTOT)
      v = (k < 10) ? SD[(size_t)m * 10 + k] : PD[(size_t)m * 207 + (k - 10)];
    Abf[(size_t)m * KP + k] = f2bf(v);
  } else {
    int idx = (bid - MPAD) * 256 + tid;   // over VPAD*32 = 221184
    if (idx < VPAD * 32) {
      int v = idx >> 5, k = idx & 31;
      Wbf[idx] = (v < V_NUM && k < NJ) ? f2bf(W[(size_t)v * NJ + k]) : (unsigned short)0;
    }
  }
}

// ---------------- Kernel B: per-batch rodrigues + joints + kinematic chain ----------------
__global__ __launch_bounds__(64) void k_batch(
    const float* __restrict__ pose, const float* __restrict__ betas,
    const float* __restrict__ trans, const float* __restrict__ JS,
    const float* __restrict__ Jt, unsigned short* __restrict__ Kcb,
    unsigned short* __restrict__ GrelP, float* __restrict__ outG,
    float* __restrict__ outJtr, int B) {
  int b = blockIdx.x;
  int lane = threadIdx.x;
  __shared__ float rotS[NJ][9];
  __shared__ float jS[NJ * 3];
  __shared__ float Gs[NJ][12];
  __shared__ float GrS[NJ][12];

  if (lane < NJ) {
    float rx = pose[b * 72 + lane * 3 + 0];
    float ry = pose[b * 72 + lane * 3 + 1];
    float rz = pose[b * 72 + lane * 3 + 2];
    float a2 = rx * rx + ry * ry + rz * rz + 1e-16f;
    float ang = sqrtf(a2);
    float inv = 1.f / ang;
    float ux = rx * inv, uy = ry * inv, uz = rz * inv;
    float c = cosf(ang), s = sinf(ang), ic = 1.f - c;
    float R[9];
    R[0] = c + ic * ux * ux;      R[1] = ic * ux * uy - s * uz; R[2] = ic * ux * uz + s * uy;
    R[3] = ic * uy * ux + s * uz; R[4] = c + ic * uy * uy;      R[5] = ic * uy * uz - s * ux;
    R[6] = ic * uz * ux - s * uy; R[7] = ic * uz * uy + s * ux; R[8] = c + ic * uz * uz;
#pragma unroll
    for (int k = 0; k < 9; k++) rotS[lane][k] = R[k];
    if (lane > 0) {
#pragma unroll
      for (int k = 0; k < 9; k++) {
        float iden = (k == 0 || k == 4 || k == 8) ? 1.f : 0.f;
        Kcb[(size_t)b * KP + 10 + (lane - 1) * 9 + k] = f2bf(R[k] - iden);
      }
    }
  }
  if (lane < 10) Kcb[(size_t)b * KP + lane] = f2bf(betas[b * 10 + lane]);
  if (lane < KP - KTOT) Kcb[(size_t)b * KP + KTOT + lane] = 0;

  __syncthreads();
  for (int idx = lane; idx < 72; idx += 64) {
    float s = Jt[idx];
#pragma unroll
    for (int ss = 0; ss < 10; ss++) s += JS[idx * 10 + ss] * betas[b * 10 + ss];
    jS[idx] = s;
  }
  __syncthreads();

  if (lane == 0) {
#pragma unroll
    for (int p = 0; p < 3; p++) {
      Gs[0][p * 4 + 0] = rotS[0][p * 3 + 0];
      Gs[0][p * 4 + 1] = rotS[0][p * 3 + 1];
      Gs[0][p * 4 + 2] = rotS[0][p * 3 + 2];
      Gs[0][p * 4 + 3] = jS[p];
    }
    for (int i = 1; i < NJ; i++) {
      int par = c_parents[i];
      float t0 = jS[i * 3 + 0] - jS[par * 3 + 0];
      float t1 = jS[i * 3 + 1] - jS[par * 3 + 1];
      float t2 = jS[i * 3 + 2] - jS[par * 3 + 2];
#pragma unroll
      for (int p = 0; p < 3; p++) {
        float rp0 = Gs[par][p * 4 + 0], rp1 = Gs[par][p * 4 + 1], rp2 = Gs[par][p * 4 + 2];
#pragma unroll
        for (int q = 0; q < 3; q++) {
          Gs[i][p * 4 + q] = rp0 * rotS[i][0 * 3 + q] + rp1 * rotS[i][1 * 3 + q] + rp2 * rotS[i][2 * 3 + q];
        }
        Gs[i][p * 4 + 3] = rp0 * t0 + rp1 * t1 + rp2 * t2 + Gs[par][p * 4 + 3];
      }
    }
    for (int i = 0; i < NJ; i++) {
      float jx = jS[i * 3 + 0], jy = jS[i * 3 + 1], jz = jS[i * 3 + 2];
#pragma unroll
      for (int p = 0; p < 3; p++) {
        float g0 = Gs[i][p * 4 + 0], g1 = Gs[i][p * 4 + 1], g2 = Gs[i][p * 4 + 2];
        GrS[i][p * 4 + 0] = g0;
        GrS[i][p * 4 + 1] = g1;
        GrS[i][p * 4 + 2] = g2;
        GrS[i][p * 4 + 3] = Gs[i][p * 4 + 3] - (g0 * jx + g1 * jy + g2 * jz);
      }
    }
  }
  __syncthreads();

  for (int idx = lane; idx < NJ * 16; idx += 64) {
    int jj = idx >> 4, rc = idx & 15, p = rc >> 2, q = rc & 3;
    float val = (p < 3) ? Gs[jj][p * 4 + q] : ((q == 3) ? 1.f : 0.f);
    outG[(size_t)b * NJ * 16 + idx] = val;
  }
  for (int idx = lane; idx < NJ * 3; idx += 64) {
    int jj = idx / 3, p = idx % 3;
    outJtr[(size_t)b * NJ * 3 + idx] = Gs[jj][p * 4 + 3] + trans[b * 3 + p];
  }
  // GrelT bf16 panel: [c=0..15][j=0..39], zeros outside c<12, j<24
  for (int idx = lane; idx < 16 * 40; idx += 64) {
    int c = idx / 40, j = idx % 40;
    GrelP[(size_t)b * 640 + idx] = (c < 12 && j < NJ) ? f2bf(GrS[j][c]) : (unsigned short)0;
  }
}

// ---------------- Kernel C: MFMA GEMM, double-buffered K chunks (stage-early) ----------------
// LDS 64KB: buf c in [c*32768, c*32768+32768): At = +0 (Kcb rows), Bt = +16384 (Abf rows).
// Per kt: issue stage(kt+1) -> buf^1 FIRST, then MFMA on buf, then __syncthreads
// (drain happens after compute -> load latency hidden under MFMA).
__global__ __launch_bounds__(256) void k_pose_mfma(
    const unsigned short* __restrict__ Kcb, const unsigned short* __restrict__ Abf,
    const float* __restrict__ VT, float* __restrict__ outVP, int B) {
  __shared__ char ldsraw[65536];
  float* stage = (float*)ldsraw;                 // epilogue: [32][132] = 16896B
  float* vtS   = (float*)(ldsraw + 17408);       // epilogue: 128 floats

  const int tid = threadIdx.x;
  const int lane = tid & 63;
  const int w = tid >> 6;
  const int wr = w >> 1, wc = w & 1;       // wr -> m half, wc -> b half
  const int b0 = blockIdx.y * 128;
  const int m0 = blockIdx.x * 128;

  f32x4 acc[4][4];
#pragma unroll
  for (int i = 0; i < 4; i++)
#pragma unroll
    for (int j = 0; j < 4; j++) acc[i][j] = (f32x4){0.f, 0.f, 0.f, 0.f};

  int Lrow[4], Lkb[4];
#pragma unroll
  for (int i = 0; i < 4; i++) {
    int L = w * 4096 + i * 1024 + lane * 16;
    int row = L >> 7;
    int kb = (L & 127) ^ ((row & 7) << 4);
    Lrow[i] = row;
    Lkb[i] = kb >> 1;
  }

  // stage chunk kt into buffer c
#define STAGE(kt, c)                                                              \
  {                                                                               \
    char* bufA = ldsraw + (c) * 32768;                                            \
    char* bufB = bufA + 16384;                                                    \
    _Pragma("unroll")                                                             \
    for (int i = 0; i < 4; i++) {                                                 \
      const unsigned short* gA = Kcb + (size_t)(b0 + Lrow[i]) * KP + (kt) * 64 + Lkb[i]; \
      gl_lds16(gA, bufA + w * 4096 + i * 1024);                                   \
      const unsigned short* gB = Abf + (size_t)(m0 + Lrow[i]) * KP + (kt) * 64 + Lkb[i]; \
      gl_lds16(gB, bufB + w * 4096 + i * 1024);                                   \
    }                                                                             \
  }

  STAGE(0, 0);
  __syncthreads();

#pragma unroll
  for (int kt = 0; kt < 4; ++kt) {
    int cur = kt & 1;
    if (kt < 3) STAGE(kt + 1, cur ^ 1);     // issue next chunk; flies during MFMA
    const char* At = ldsraw + cur * 32768;
    const char* Bt = At + 16384;
#pragma unroll
    for (int h = 0; h < 2; ++h) {
      bf16x8 fm[4], fb[4];
#pragma unroll
      for (int fi = 0; fi < 4; fi++) {
        int row = wr * 64 + fi * 16 + (lane & 15);
        int byte = (row << 7) + ((h * 64 + ((lane >> 4) << 4)) ^ ((row & 7) << 4));
        fm[fi] = *(const bf16x8*)(Bt + byte);
      }
#pragma unroll
      for (int fj = 0; fj < 4; fj++) {
        int row = wc * 64 + fj * 16 + (lane & 15);
        int byte = (row << 7) + ((h * 64 + ((lane >> 4) << 4)) ^ ((row & 7) << 4));
        fb[fj] = *(const bf16x8*)(At + byte);
      }
#pragma unroll
      for (int fi = 0; fi < 4; fi++)
#pragma unroll
        for (int fj = 0; fj < 4; fj++)
          acc[fi][fj] = __builtin_amdgcn_mfma_f32_16x16x32_bf16(fm[fi], fb[fj], acc[fi][fj], 0, 0, 0);
    }
    __syncthreads();   // drains staged loads (overlapped with MFMA above) + reuse fence
  }
#undef STAGE

  // epilogue: VT into LDS, then 4 staged passes with coalesced float4 writes
  if (tid < 128) vtS[tid] = (m0 + tid < M_DIM) ? VT[m0 + tid] : 0.f;
#pragma unroll
  for (int pp = 0; pp < 4; pp++) {
    __syncthreads();
    {
      int rowIdx = wc * 16 + (lane & 15);
#pragma unroll
      for (int fi = 0; fi < 4; fi++) {
        int ml = wr * 64 + fi * 16 + ((lane >> 4) << 2);
        *(f32x4*)&stage[rowIdx * 132 + ml] = acc[fi][pp];
      }
    }
    __syncthreads();
    int row = tid >> 3;                       // 0..31
    int brow = ((row >> 4) * 64) + pp * 16 + (row & 15);
    size_t gb = (size_t)(b0 + brow) * M_DIM;
#pragma unroll
    for (int i = 0; i < 4; i++) {
      int col4 = (tid & 7) + 8 * i;           // 0..31
      int mg = m0 + col4 * 4;
      f32x4 v = *(f32x4*)&stage[row * 132 + col4 * 4];
      f32x4 vt = *(f32x4*)&vtS[col4 * 4];
      v = v + vt;
      if (mg + 3 < M_DIM) {
        *(f32x4*)(outVP + gb + mg) = v;
      } else {
#pragma unroll
        for (int r = 0; r < 4; r++)
          if (mg + r < M_DIM) outVP[gb + mg + r] = v[r];
      }
    }
  }
}

// ---------------- Kernel D: MFMA skinning, dependency-flattened ----------------
// All 8 Grel fragments prefetched upfront; x 1-ahead; NO asm barriers — per-wave
// LDS ops are in-order (scatter->gather needs no explicit wait), compiler free to
// software-pipeline the 8 unrolled iterations.
__global__ __launch_bounds__(256) void k_skin6(
    const float* __restrict__ VP, const unsigned short* __restrict__ Wbf,
    const unsigned short* __restrict__ GrelP, const float* __restrict__ trans,
    float* __restrict__ outNK, float* __restrict__ outVerts, int B) {
  __shared__ float Tl[4][64 * 13];
  const int tid = threadIdx.x;
  const int lane = tid & 63;
  const int w = tid >> 6;
  const int vl16 = lane & 15;
  const int p = lane >> 4;        // c-row group (3 = zero rows)
  const int kb = p * 8;           // k-base of this lane's fragment
  const int vbase = blockIdx.x * 256 + w * 64;
  const int b0 = blockIdx.y * 8;
  const int vg = vbase + lane;    // this lane's owned vert
  const bool vok = vg < V_NUM;

  // W B-fragments, reused across 8 batches (rows = verts)
  bf16x8 wf[4];
#pragma unroll
  for (int sub = 0; sub < 4; sub++)
    wf[sub] = *(const bf16x8*)(Wbf + (size_t)(vbase + sub * 16 + vl16) * 32 + kb);

  // all 8 batches' Grel A-fragments (L2-hot, 32 VGPR)
  bf16x8 af[8];
#pragma unroll
  for (int bi = 0; bi < 8; bi++)
    af[bi] = *(const bf16x8*)(GrelP + (size_t)(b0 + bi) * 640 + vl16 * 40 + kb);

  float* myT = Tl[w];

  // x-vector 1-ahead prefetch
  float xc0 = 0.f, xc1 = 0.f, xc2 = 0.f;
  if (vok) {
    const float* xp = VP + (size_t)b0 * M_DIM + (size_t)vg * 3;
    xc0 = xp[0]; xc1 = xp[1]; xc2 = xp[2];
  }

#pragma unroll
  for (int bi = 0; bi < 8; bi++) {
    int b = b0 + bi;
    f32x4 acc[4];
#pragma unroll
    for (int sub = 0; sub < 4; sub++) {
      f32x4 z = (f32x4){0.f, 0.f, 0.f, 0.f};
      acc[sub] = __builtin_amdgcn_mfma_f32_16x16x32_bf16(af[bi], wf[sub], z, 0, 0, 0);
    }
    // scatter T to LDS: T[vert][c], c = p*4 + r  (wave-private plane, in-order DS)
    if (p < 3) {
#pragma unroll
      for (int sub = 0; sub < 4; sub++) {
        int vi = sub * 16 + vl16;
#pragma unroll
        for (int r = 0; r < 4; r++)
          myT[vi * 13 + p * 4 + r] = acc[sub][r];
      }
    }
    // next x-vector (independent; flies under gather+apply)
    float xn0 = 0.f, xn1 = 0.f, xn2 = 0.f;
    if (bi < 7 && vok) {
      const float* xp = VP + (size_t)(b + 1) * M_DIM + (size_t)vg * 3;
      xn0 = xp[0]; xn1 = xp[1]; xn2 = xp[2];
    }
    // per-lane vert gather + apply (coalesced); NK copy independent of T
    if (vok) {
      size_t base = (size_t)b * M_DIM + (size_t)vg * 3;
      float* onk = outNK + base;
      onk[0] = xc0; onk[1] = xc1; onk[2] = xc2;
      float t[12];
#pragma unroll
      for (int c = 0; c < 12; c++) t[c] = myT[lane * 13 + c];
      float* op = outVerts + base;
      op[0] = t[0] * xc0 + t[1] * xc1 + t[2] * xc2 + t[3] + trans[b * 3 + 0];
      op[1] = t[4] * xc0 + t[5] * xc1 + t[6] * xc2 + t[7] + trans[b * 3 + 1];
      op[2] = t[8] * xc0 + t[9] * xc1 + t[10] * xc2 + t[11] + trans[b * 3 + 2];
    }
    xc0 = xn0; xc1 = xn1; xc2 = xn2;
  }
}

extern "C" void kernel_launch(void* const* d_in, const int* in_sizes, int n_in,
                              void* d_out, int out_size, void* d_ws, size_t ws_size,
                              hipStream_t stream) {
  const float* pose  = (const float*)d_in[0];
  const float* betas = (const float*)d_in[1];
  const float* trans = (const float*)d_in[2];
  const float* vt    = (const float*)d_in[3];
  const float* sd    = (const float*)d_in[4];
  const float* pd    = (const float*)d_in[5];
  const float* jreg  = (const float*)d_in[6];
  const float* wgt   = (const float*)d_in[7];
  int B = in_sizes[0] / 72;

  float* out = (float*)d_out;
  size_t nvb = (size_t)B * M_DIM;
  float* o_verts = out;
  float* o_jtr   = o_verts + nvb;
  float* o_vp    = o_jtr + (size_t)B * NJ * 3;
  float* o_nk    = o_vp + nvb;
  float* o_G     = o_nk + nvb;

  char* wsb = (char*)d_ws;
  float* JS = (float*)wsb;                          // 720 f32
  float* Jt = JS + 720;                             // 72 f32
  size_t off = (720 + 72) * 4;                      // 3168 B (16-aligned)
  unsigned short* Kcb   = (unsigned short*)(wsb + off);                       // B*KP
  unsigned short* Abf   = (unsigned short*)(wsb + off + (size_t)B * KP * 2);  // MPAD*KP
  unsigned short* GrelP = Abf + (size_t)MPAD * KP;                            // B*640
  unsigned short* Wbf   = GrelP + (size_t)B * 640;                            // VPAD*32

  k_regress<<<24, 256, 0, stream>>>(jreg, sd, vt, JS, Jt);
  k_conv<<<MPAD + (VPAD * 32 + 255) / 256, 256, 0, stream>>>(sd, pd, wgt, Abf, Wbf);
  k_batch<<<B, 64, 0, stream>>>(pose, betas, trans, JS, Jt, Kcb, GrelP, o_G, o_jtr, B);
  dim3 gC(MPAD / 128, B / 128);
  k_pose_mfma<<<gC, 256, 0, stream>>>(Kcb, Abf, vt, o_vp, B);
  dim3 gD(VPAD / 256, B / 8);
  k_skin6<<<gD, 256, 0, stream>>>(o_vp, Wbf, GrelP, trans, o_nk, o_verts, B);
}

// Round 9
// 147.506 us; speedup vs baseline: 1.3545x; 1.0266x over previous
//
#include <hip/hip_runtime.h>
#include <math.h>

#define V_NUM 6890
#define NJ 24
#define KTOT 217            // 10 betas + 207 pose_map
#define KP 256              // padded K (multiple of 64)
#define M_DIM (V_NUM * 3)   // 20670
#define MPAD 20736          // 162 * 128
#define VPAD 6912           // 27 * 256

typedef __attribute__((ext_vector_type(8))) short bf16x8;
typedef __attribute__((ext_vector_type(4))) float f32x4;

__constant__ int c_parents[NJ] = {-1,0,0,0,1,2,3,4,5,6,7,8,9,9,9,12,13,14,16,17,18,19,20,21};

__device__ __forceinline__ unsigned short f2bf(float x) {
  union { float f; unsigned int u; } v; v.f = x;
  unsigned int r = v.u + 0x7fffu + ((v.u >> 16) & 1u);
  return (unsigned short)(r >> 16);
}

#define GLOBAL_AS __attribute__((address_space(1)))
#define LDS_AS __attribute__((address_space(3)))
__device__ __forceinline__ void gl_lds16(const void* g, void* l) {
  __builtin_amdgcn_global_load_lds((const GLOBAL_AS unsigned int*)g,
                                   (LDS_AS unsigned int*)l, 16, 0, 0);
}

// ---------------- Kernel A: J_regressor fold, one output scalar per block ----------------
// block (j, q): out = dot(JR[j,:], col q) where col q<30 -> SD[:,q], else VT[:,q-30].
// 792 blocks (vs old 24) -> full-GPU latency hiding; JR row reads coalesced.
__global__ __launch_bounds__(256) void k_regress2(
    const float* __restrict__ JR, const float* __restrict__ SD,
    const float* __restrict__ VT, float* __restrict__ JS, float* __restrict__ Jt) {
  int j = blockIdx.x;
  int q = blockIdx.y;
  int tid = threadIdx.x;
  float part = 0.f;
  const float* jr = JR + (size_t)j * V_NUM;
  if (q < 30) {
    for (int v = tid; v < V_NUM; v += 256)
      part += jr[v] * SD[(size_t)v * 30 + q];
  } else {
    int cc = q - 30;
    for (int v = tid; v < V_NUM; v += 256)
      part += jr[v] * VT[(size_t)v * 3 + cc];
  }
  for (int off = 32; off > 0; off >>= 1) part += __shfl_down(part, off);
  __shared__ float sm[4];
  if ((tid & 63) == 0) sm[tid >> 6] = part;
  __syncthreads();
  if (tid == 0) {
    float s = sm[0] + sm[1] + sm[2] + sm[3];
    if (q < 30) JS[j * 30 + q] = s;
    else Jt[j * 3 + (q - 30)] = s;
  }
}

// ---------------- Kernel A2: convert A -> bf16 [MPAD][KP]  AND  W -> bf16 [VPAD][32] ----------------
__global__ __launch_bounds__(256) void k_conv(
    const float* __restrict__ SD, const float* __restrict__ PD,
    const float* __restrict__ W,
    unsigned short* __restrict__ Abf, unsigned short* __restrict__ Wbf) {
  int bid = blockIdx.x;
  int tid = threadIdx.x;
  if (bid < MPAD) {
    int m = bid, k = tid;
    float v = 0.f;
    if (m < M_DIM && k < KTOT)
      v = (k < 10) ? SD[(size_t)m * 10 + k] : PD[(size_t)m * 207 + (k - 10)];
    Abf[(size_t)m * KP + k] = f2bf(v);
  } else {
    int idx = (bid - MPAD) * 256 + tid;   // over VPAD*32 = 221184
    if (idx < VPAD * 32) {
      int v = idx >> 5, k = idx & 31;
      Wbf[idx] = (v < V_NUM && k < NJ) ? f2bf(W[(size_t)v * NJ + k]) : (unsigned short)0;
    }
  }
}

// ---------------- Kernel B: per-batch rodrigues + joints + kinematic chain ----------------
__global__ __launch_bounds__(64) void k_batch(
    const float* __restrict__ pose, const float* __restrict__ betas,
    const float* __restrict__ trans, const float* __restrict__ JS,
    const float* __restrict__ Jt, unsigned short* __restrict__ Kcb,
    unsigned short* __restrict__ GrelP, float* __restrict__ outG,
    float* __restrict__ outJtr, int B) {
  int b = blockIdx.x;
  int lane = threadIdx.x;
  __shared__ float rotS[NJ][9];
  __shared__ float jS[NJ * 3];
  __shared__ float Gs[NJ][12];
  __shared__ float GrS[NJ][12];

  if (lane < NJ) {
    float rx = pose[b * 72 + lane * 3 + 0];
    float ry = pose[b * 72 + lane * 3 + 1];
    float rz = pose[b * 72 + lane * 3 + 2];
    float a2 = rx * rx + ry * ry + rz * rz + 1e-16f;
    float ang = sqrtf(a2);
    float inv = 1.f / ang;
    float ux = rx * inv, uy = ry * inv, uz = rz * inv;
    float c = cosf(ang), s = sinf(ang), ic = 1.f - c;
    float R[9];
    R[0] = c + ic * ux * ux;      R[1] = ic * ux * uy - s * uz; R[2] = ic * ux * uz + s * uy;
    R[3] = ic * uy * ux + s * uz; R[4] = c + ic * uy * uy;      R[5] = ic * uy * uz - s * ux;
    R[6] = ic * uz * ux - s * uy; R[7] = ic * uz * uy + s * ux; R[8] = c + ic * uz * uz;
#pragma unroll
    for (int k = 0; k < 9; k++) rotS[lane][k] = R[k];
    if (lane > 0) {
#pragma unroll
      for (int k = 0; k < 9; k++) {
        float iden = (k == 0 || k == 4 || k == 8) ? 1.f : 0.f;
        Kcb[(size_t)b * KP + 10 + (lane - 1) * 9 + k] = f2bf(R[k] - iden);
      }
    }
  }
  if (lane < 10) Kcb[(size_t)b * KP + lane] = f2bf(betas[b * 10 + lane]);
  if (lane < KP - KTOT) Kcb[(size_t)b * KP + KTOT + lane] = 0;

  __syncthreads();
  for (int idx = lane; idx < 72; idx += 64) {
    float s = Jt[idx];
#pragma unroll
    for (int ss = 0; ss < 10; ss++) s += JS[idx * 10 + ss] * betas[b * 10 + ss];
    jS[idx] = s;
  }
  __syncthreads();

  if (lane == 0) {
#pragma unroll
    for (int p = 0; p < 3; p++) {
      Gs[0][p * 4 + 0] = rotS[0][p * 3 + 0];
      Gs[0][p * 4 + 1] = rotS[0][p * 3 + 1];
      Gs[0][p * 4 + 2] = rotS[0][p * 3 + 2];
      Gs[0][p * 4 + 3] = jS[p];
    }
    for (int i = 1; i < NJ; i++) {
      int par = c_parents[i];
      float t0 = jS[i * 3 + 0] - jS[par * 3 + 0];
      float t1 = jS[i * 3 + 1] - jS[par * 3 + 1];
      float t2 = jS[i * 3 + 2] - jS[par * 3 + 2];
#pragma unroll
      for (int p = 0; p < 3; p++) {
        float rp0 = Gs[par][p * 4 + 0], rp1 = Gs[par][p * 4 + 1], rp2 = Gs[par][p * 4 + 2];
#pragma unroll
        for (int q = 0; q < 3; q++) {
          Gs[i][p * 4 + q] = rp0 * rotS[i][0 * 3 + q] + rp1 * rotS[i][1 * 3 + q] + rp2 * rotS[i][2 * 3 + q];
        }
        Gs[i][p * 4 + 3] = rp0 * t0 + rp1 * t1 + rp2 * t2 + Gs[par][p * 4 + 3];
      }
    }
    for (int i = 0; i < NJ; i++) {
      float jx = jS[i * 3 + 0], jy = jS[i * 3 + 1], jz = jS[i * 3 + 2];
#pragma unroll
      for (int p = 0; p < 3; p++) {
        float g0 = Gs[i][p * 4 + 0], g1 = Gs[i][p * 4 + 1], g2 = Gs[i][p * 4 + 2];
        GrS[i][p * 4 + 0] = g0;
        GrS[i][p * 4 + 1] = g1;
        GrS[i][p * 4 + 2] = g2;
        GrS[i][p * 4 + 3] = Gs[i][p * 4 + 3] - (g0 * jx + g1 * jy + g2 * jz);
      }
    }
  }
  __syncthreads();

  for (int idx = lane; idx < NJ * 16; idx += 64) {
    int jj = idx >> 4, rc = idx & 15, p = rc >> 2, q = rc & 3;
    float val = (p < 3) ? Gs[jj][p * 4 + q] : ((q == 3) ? 1.f : 0.f);
    outG[(size_t)b * NJ * 16 + idx] = val;
  }
  for (int idx = lane; idx < NJ * 3; idx += 64) {
    int jj = idx / 3, p = idx % 3;
    outJtr[(size_t)b * NJ * 3 + idx] = Gs[jj][p * 4 + 3] + trans[b * 3 + p];
  }
  // GrelT bf16 panel: [c=0..15][j=0..39], zeros outside c<12, j<24
  for (int idx = lane; idx < 16 * 40; idx += 64) {
    int c = idx / 40, j = idx % 40;
    GrelP[(size_t)b * 640 + idx] = (c < 12 && j < NJ) ? f2bf(GrS[j][c]) : (unsigned short)0;
  }
}

// ---------------- Kernel C: MFMA GEMM, dbuf K chunks + BARRIER-FREE wave-private epilogue ----------------
// k-loop: stage(kt+1) issued before MFMA(kt) (loads fly under compute).
// Epilogue: per wave, per fj: scatter acc into a private 4.25KB LDS slab
// (16 b-rows x 68 m-floats, 16B-block XOR swizzle) then read back b128 per-vert-row
// and store 64B-contiguous float4 runs. No __syncthreads -> no vmcnt(0) store drains.
__global__ __launch_bounds__(256) void k_pose_mfma(
    const unsigned short* __restrict__ Kcb, const unsigned short* __restrict__ Abf,
    const float* __restrict__ VT, float* __restrict__ outVP, int B) {
  __shared__ char ldsraw[65536];

  const int tid = threadIdx.x;
  const int lane = tid & 63;
  const int w = tid >> 6;
  const int wr = w >> 1, wc = w & 1;       // wr -> m half, wc -> b half
  const int b0 = blockIdx.y * 128;
  const int m0 = blockIdx.x * 128;

  // VT in reader layout: lane (a=lane&15, c=lane>>4) stores m = m0+wr*64+c*16+i*4+r
  f32x4 vt4[4];
  {
    int mbase = m0 + wr * 64 + ((lane >> 4) << 4);
#pragma unroll
    for (int i = 0; i < 4; i++) {
      int mm = mbase + i * 4;
      if (mm + 3 < M_DIM) vt4[i] = *(const f32x4*)(VT + mm);
      else {
#pragma unroll
        for (int r = 0; r < 4; r++) vt4[i][r] = (mm + r < M_DIM) ? VT[mm + r] : 0.f;
      }
    }
  }

  f32x4 acc[4][4];
#pragma unroll
  for (int i = 0; i < 4; i++)
#pragma unroll
    for (int j = 0; j < 4; j++) acc[i][j] = (f32x4){0.f, 0.f, 0.f, 0.f};

  int Lrow[4], Lkb[4];
#pragma unroll
  for (int i = 0; i < 4; i++) {
    int L = w * 4096 + i * 1024 + lane * 16;
    int row = L >> 7;
    int kb = (L & 127) ^ ((row & 7) << 4);
    Lrow[i] = row;
    Lkb[i] = kb >> 1;
  }

#define STAGE(kt, c)                                                              \
  {                                                                               \
    char* bufA = ldsraw + (c) * 32768;                                            \
    char* bufB = bufA + 16384;                                                    \
    _Pragma("unroll")                                                             \
    for (int i = 0; i < 4; i++) {                                                 \
      const unsigned short* gA = Kcb + (size_t)(b0 + Lrow[i]) * KP + (kt) * 64 + Lkb[i]; \
      gl_lds16(gA, bufA + w * 4096 + i * 1024);                                   \
      const unsigned short* gB = Abf + (size_t)(m0 + Lrow[i]) * KP + (kt) * 64 + Lkb[i]; \
      gl_lds16(gB, bufB + w * 4096 + i * 1024);                                   \
    }                                                                             \
  }

  STAGE(0, 0);
  __syncthreads();

#pragma unroll
  for (int kt = 0; kt < 4; ++kt) {
    int cur = kt & 1;
    if (kt < 3) STAGE(kt + 1, cur ^ 1);     // issue next chunk; flies during MFMA
    const char* At = ldsraw + cur * 32768;
    const char* Bt = At + 16384;
#pragma unroll
    for (int h = 0; h < 2; ++h) {
      bf16x8 fm[4], fb[4];
#pragma unroll
      for (int fi = 0; fi < 4; fi++) {
        int row = wr * 64 + fi * 16 + (lane & 15);
        int byte = (row << 7) + ((h * 64 + ((lane >> 4) << 4)) ^ ((row & 7) << 4));
        fm[fi] = *(const bf16x8*)(Bt + byte);
      }
#pragma unroll
      for (int fj = 0; fj < 4; fj++) {
        int row = wc * 64 + fj * 16 + (lane & 15);
        int byte = (row << 7) + ((h * 64 + ((lane >> 4) << 4)) ^ ((row & 7) << 4));
        fb[fj] = *(const bf16x8*)(At + byte);
      }
#pragma unroll
      for (int fi = 0; fi < 4; fi++)
#pragma unroll
        for (int fj = 0; fj < 4; fj++)
          acc[fi][fj] = __builtin_amdgcn_mfma_f32_16x16x32_bf16(fm[fi], fb[fj], acc[fi][fj], 0, 0, 0);
    }
    __syncthreads();   // drains staged loads (overlapped with MFMA) + buffer reuse fence
  }
#undef STAGE

  // barrier-free wave-private epilogue (LDS k-bufs no longer needed; last barrier above)
  char* wslab = ldsraw + w * 4352;          // 16 rows x 272 B
  const int a = lane & 15, c = lane >> 4;
  const int xr = (lane & 3) << 4;           // 16B-block XOR key (= a&3)
#pragma unroll
  for (int fj = 0; fj < 4; fj++) {
    // scatter: lane's acc[fi][fj] -> row a, m-local col (fi*16 + c*4), block-XOR by a&3
#pragma unroll
    for (int fi = 0; fi < 4; fi++) {
      int off = a * 272 + (((fi << 6) + (c << 4)) ^ xr);
      *(f32x4*)(wslab + off) = acc[fi][fj];
    }
    // gather: lane owns b-row a, m-chunk c (16 floats = 4 xf32x4), un-XOR by a&3
    int brow = b0 + wc * 64 + fj * 16 + a;
    size_t gb = (size_t)brow * M_DIM;
    int mg0 = m0 + wr * 64 + (c << 4);
#pragma unroll
    for (int i = 0; i < 4; i++) {
      int off = a * 272 + (((c << 6) + (i << 4)) ^ xr);
      f32x4 v = *(f32x4*)(wslab + off);
      v = v + vt4[i];
      int mg = mg0 + i * 4;
      if (mg + 3 < M_DIM) {
        *(f32x4*)(outVP + gb + mg) = v;
      } else {
#pragma unroll
        for (int r = 0; r < 4; r++)
          if (mg + r < M_DIM) outVP[gb + mg + r] = v[r];
      }
    }
  }
}

// ---------------- Kernel D: MFMA skinning, 4 batches/block (2x TLP) ----------------
__global__ __launch_bounds__(256) void k_skin7(
    const float* __restrict__ VP, const unsigned short* __restrict__ Wbf,
    const unsigned short* __restrict__ GrelP, const float* __restrict__ trans,
    float* __restrict__ outNK, float* __restrict__ outVerts, int B) {
  __shared__ float Tl[4][64 * 13];
  const int tid = threadIdx.x;
  const int lane = tid & 63;
  const int w = tid >> 6;
  const int vl16 = lane & 15;
  const int p = lane >> 4;        // c-row group (3 = zero rows)
  const int kb = p * 8;           // k-base of this lane's fragment
  const int vbase = blockIdx.x * 256 + w * 64;
  const int b0 = blockIdx.y * 4;
  const int vg = vbase + lane;    // this lane's owned vert
  const bool vok = vg < V_NUM;

  bf16x8 wf[4];
#pragma unroll
  for (int sub = 0; sub < 4; sub++)
    wf[sub] = *(const bf16x8*)(Wbf + (size_t)(vbase + sub * 16 + vl16) * 32 + kb);

  bf16x8 af[4];
#pragma unroll
  for (int bi = 0; bi < 4; bi++)
    af[bi] = *(const bf16x8*)(GrelP + (size_t)(b0 + bi) * 640 + vl16 * 40 + kb);

  float* myT = Tl[w];

  float xc0 = 0.f, xc1 = 0.f, xc2 = 0.f;
  if (vok) {
    const float* xp = VP + (size_t)b0 * M_DIM + (size_t)vg * 3;
    xc0 = xp[0]; xc1 = xp[1]; xc2 = xp[2];
  }

#pragma unroll
  for (int bi = 0; bi < 4; bi++) {
    int b = b0 + bi;
    f32x4 acc[4];
#pragma unroll
    for (int sub = 0; sub < 4; sub++) {
      f32x4 z = (f32x4){0.f, 0.f, 0.f, 0.f};
      acc[sub] = __builtin_amdgcn_mfma_f32_16x16x32_bf16(af[bi], wf[sub], z, 0, 0, 0);
    }
    if (p < 3) {
#pragma unroll
      for (int sub = 0; sub < 4; sub++) {
        int vi = sub * 16 + vl16;
#pragma unroll
        for (int r = 0; r < 4; r++)
          myT[vi * 13 + p * 4 + r] = acc[sub][r];
      }
    }
    float xn0 = 0.f, xn1 = 0.f, xn2 = 0.f;
    if (bi < 3 && vok) {
      const float* xp = VP + (size_t)(b + 1) * M_DIM + (size_t)vg * 3;
      xn0 = xp[0]; xn1 = xp[1]; xn2 = xp[2];
    }
    if (vok) {
      size_t base = (size_t)b * M_DIM + (size_t)vg * 3;
      float* onk = outNK + base;
      onk[0] = xc0; onk[1] = xc1; onk[2] = xc2;
      float t[12];
#pragma unroll
      for (int c = 0; c < 12; c++) t[c] = myT[lane * 13 + c];
      float* op = outVerts + base;
      op[0] = t[0] * xc0 + t[1] * xc1 + t[2] * xc2 + t[3] + trans[b * 3 + 0];
      op[1] = t[4] * xc0 + t[5] * xc1 + t[6] * xc2 + t[7] + trans[b * 3 + 1];
      op[2] = t[8] * xc0 + t[9] * xc1 + t[10] * xc2 + t[11] + trans[b * 3 + 2];
    }
    xc0 = xn0; xc1 = xn1; xc2 = xn2;
  }
}

extern "C" void kernel_launch(void* const* d_in, const int* in_sizes, int n_in,
                              void* d_out, int out_size, void* d_ws, size_t ws_size,
                              hipStream_t stream) {
  const float* pose  = (const float*)d_in[0];
  const float* betas = (const float*)d_in[1];
  const float* trans = (const float*)d_in[2];
  const float* vt    = (const float*)d_in[3];
  const float* sd    = (const float*)d_in[4];
  const float* pd    = (const float*)d_in[5];
  const float* jreg  = (const float*)d_in[6];
  const float* wgt   = (const float*)d_in[7];
  int B = in_sizes[0] / 72;

  float* out = (float*)d_out;
  size_t nvb = (size_t)B * M_DIM;
  float* o_verts = out;
  float* o_jtr   = o_verts + nvb;
  float* o_vp    = o_jtr + (size_t)B * NJ * 3;
  float* o_nk    = o_vp + nvb;
  float* o_G     = o_nk + nvb;

  char* wsb = (char*)d_ws;
  float* JS = (float*)wsb;                          // 720 f32
  float* Jt = JS + 720;                             // 72 f32
  size_t off = (720 + 72) * 4;                      // 3168 B (16-aligned)
  unsigned short* Kcb   = (unsigned short*)(wsb + off);                       // B*KP
  unsigned short* Abf   = (unsigned short*)(wsb + off + (size_t)B * KP * 2);  // MPAD*KP
  unsigned short* GrelP = Abf + (size_t)MPAD * KP;                            // B*640
  unsigned short* Wbf   = GrelP + (size_t)B * 640;                            // VPAD*32

  dim3 gR(24, 33);
  k_regress2<<<gR, 256, 0, stream>>>(jreg, sd, vt, JS, Jt);
  k_conv<<<MPAD + (VPAD * 32 + 255) / 256, 256, 0, stream>>>(sd, pd, wgt, Abf, Wbf);
  k_batch<<<B, 64, 0, stream>>>(pose, betas, trans, JS, Jt, Kcb, GrelP, o_G, o_jtr, B);
  dim3 gC(MPAD / 128, B / 128);
  k_pose_mfma<<<gC, 256, 0, stream>>>(Kcb, Abf, vt, o_vp, B);
  dim3 gD(VPAD / 256, B / 4);
  k_skin7<<<gD, 256, 0, stream>>>(o_vp, Wbf, GrelP, trans, o_nk, o_verts, B);
}